// Round 14
// baseline (152.129 us; speedup 1.0000x reference)
//
#include <hip/hip_runtime.h>
#include <math.h>

#define N_PTS 2097152
#define TAILC 0.53974324f   // log(exp(1-0.001)-1)
#define LOG2E 1.4426950408889634f
#define LN2   0.6931471805599453f

typedef unsigned int u32;
typedef _Float16 half8 __attribute__((ext_vector_type(8)));
typedef _Float16 half4 __attribute__((ext_vector_type(4)));
typedef _Float16 h2    __attribute__((ext_vector_type(2)));
typedef __fp16   fp16x2 __attribute__((ext_vector_type(2)));
typedef float float4v  __attribute__((ext_vector_type(4)));

#define MFMA16 __builtin_amdgcn_mfma_f32_16x16x32_f16

__device__ __forceinline__ float lrelu(float x){ return x > 0.0f ? x : 0.01f*x; }
__device__ __forceinline__ float exp2fast(float x){
#if __has_builtin(__builtin_amdgcn_exp2f)
    return __builtin_amdgcn_exp2f(x);
#else
    return exp2f(x);
#endif
}
__device__ __forceinline__ float log2fast(float x){
#if __has_builtin(__builtin_amdgcn_logf)
    return __builtin_amdgcn_logf(x);
#else
    return __log2f(x);
#endif
}
// softplus(x) = ln2 * log2(1 + exp2(x*log2e)); f32-safe for |x| < ~80
__device__ __forceinline__ float softplus_(float x){
    return LN2 * log2fast(1.0f + exp2fast(x * LOG2E));
}
__device__ __forceinline__ half4 pack4(float a0, float a1, float a2, float a3){
#if __has_builtin(__builtin_amdgcn_cvt_pkrtz)
    union { fp16x2 f; h2 h; } lo, hi;
    lo.f = __builtin_amdgcn_cvt_pkrtz(a0, a1);
    hi.f = __builtin_amdgcn_cvt_pkrtz(a2, a3);
    half4 r; r[0]=lo.h[0]; r[1]=lo.h[1]; r[2]=hi.h[0]; r[3]=hi.h[1];
    return r;
#else
    half4 r; r[0]=(_Float16)a0; r[1]=(_Float16)a1; r[2]=(_Float16)a2; r[3]=(_Float16)a3;
    return r;
#endif
}
// packed f16 leaky-relu: v_pk_mul_f16 + v_pk_max_f16 via elementwise builtins
__device__ __forceinline__ h2 lrelu2(h2 x){
#if __has_builtin(__builtin_elementwise_max)
    h2 m = x * (_Float16)0.01f;
    return __builtin_elementwise_max(x, m);
#else
    h2 r; r[0] = (x[0] > (_Float16)0 ? x[0] : x[0]*(_Float16)0.01f);
    r[1] = (x[1] > (_Float16)0 ? x[1] : x[1]*(_Float16)0.01f);
    return r;
#endif
}
// pack 4 f32 -> 4 f16 then leaky-relu in PACKED f16
__device__ __forceinline__ half4 pack4_lrelu(float a0, float a1, float a2, float a3){
#if __has_builtin(__builtin_amdgcn_cvt_pkrtz)
    union { fp16x2 f; h2 h; } lo, hi;
    lo.f = __builtin_amdgcn_cvt_pkrtz(a0, a1);
    hi.f = __builtin_amdgcn_cvt_pkrtz(a2, a3);
    h2 lm = lrelu2(lo.h), hm = lrelu2(hi.h);
    half4 r; r[0]=lm[0]; r[1]=lm[1]; r[2]=hm[0]; r[3]=hm[1];
    return r;
#else
    return pack4(lrelu(a0), lrelu(a1), lrelu(a2), lrelu(a3));
#endif
}
__device__ __forceinline__ half8 join8(half4 a, half4 b){
    half8 r; r[0]=a[0]; r[1]=a[1]; r[2]=a[2]; r[3]=a[3];
    r[4]=b[0]; r[5]=b[1]; r[6]=b[2]; r[7]=b[3];
    return r;
}
__device__ __forceinline__ float fdot2(h2 a, h2 b, float c){
#if __has_builtin(__builtin_amdgcn_fdot2)
    return __builtin_amdgcn_fdot2(a, b, c, false);
#else
    return fmaf((float)a[0],(float)b[0], fmaf((float)a[1],(float)b[1], c));
#endif
}
__device__ __forceinline__ h2 u2h2(u32 u){ union{u32 a; h2 b;} x; x.a=u; return x.b; }

// physical position of logical output o for 32-wide layers (p = 8g + 4n + j, o = 16n+4g+j)
__device__ __host__ constexpr int ppos(int o){
    return 8*((o>>2)&3) + 4*(o>>4) + (o&3);
}
// physical position of logical output m for the 64-wide L2 layer
__device__ __host__ constexpr int qpos(int m){
    return 16*((m>>2)&3) + 8*((m>>4)>>1) + 4*((m>>4)&1) + (m&3);
}
// inverse: logical o at physical p (32-wide)
__device__ __host__ constexpr int pinv(int p){
    return 16*((p>>2)&1) + 4*(p>>3) + (p&3);
}

// Single shared allocation reachable from kernel AND noinline callees.
// 2 waves per 128-thread block -> 16KB/block -> 10 blocks/CU (20 waves, 62.5%).
__device__ __forceinline__ _Float16* waveS(){
    __shared__ _Float16 S[2][4096];    // per-wave [64 rows][64 f16], swizzled
    return &S[0][0];
}
__device__ __forceinline__ half8 rd16(const _Float16* Sw, int row, int u){
    return *(const half8*)(Sw + row*64 + ((u ^ (row&7))<<3));
}
__device__ __forceinline__ void wr16(_Float16* Sw, int row, int u, half8 v){
    *(half8*)(Sw + row*64 + ((u ^ (row&7))<<3)) = v;
}

// ---- packed weights/biases in d_ws ----
#define OFF_M1_W0T 0        // [32][64]
#define OFF_M1_W1T 2048     // [32][32]
#define OFF_M1_W2T 3072     // [64][32]
#define OFF_M0_W0T 5120
#define OFF_M0_W1T 7168
#define OFF_M0_W2T 8192
#define OFF_P0_W0T 10240    // [32][32]
#define WS_F16     11264
// f32 region (byte 22528)
#define FB_M1_B0   0
#define FB_M1_B1   32
#define FB_M1_B2   64       // padded to 64, outputs 0..39 pre-scaled by LOG2E
#define FB_M0_B0   128
#define FB_M0_B1   160
#define FB_M0_B2   192
#define FB_P0_B0   256
#define FB_PW1     288      // 64 u32: p0_w1 packed h2 pairs
#define WS_BYTES   (22528 + 288*4 + 64*4)
#define PACK_ITEMS (WS_F16 + 288 + 64)

__global__ void pack_weights(const float* __restrict__ m1_w0, const float* __restrict__ m1_w1,
                             const float* __restrict__ m1_w2, const float* __restrict__ m0_w0,
                             const float* __restrict__ m0_w1, const float* __restrict__ m0_w2,
                             const float* __restrict__ p0_w0, const float* __restrict__ p0_w1,
                             const float* __restrict__ m1_b0, const float* __restrict__ m1_b1,
                             const float* __restrict__ m1_b2, const float* __restrict__ m0_b0,
                             const float* __restrict__ m0_b1, const float* __restrict__ m0_b2,
                             const float* __restrict__ p0_b0, _Float16* __restrict__ ws)
{
    int idx = blockIdx.x*256 + threadIdx.x;
    if (idx >= PACK_ITEMS) return;
    if (idx < WS_F16) {
        float v = 0.0f;
        if (idx < 2048 || (idx >= 5120 && idx < 7168)) {          // W0T [32][64], k logical
            const float* W = (idx < 2048) ? m1_w0 : m0_w0;
            int r = (idx < 2048) ? idx : idx - 5120;
            int o = r >> 6, k = r & 63;
            if (k < 30)                 v = W[(9+k)*32 + o];
            else if (k >= 32 && k < 41) v = W[(k-32)*32 + o];
        } else if (idx < 3072 || (idx >= 7168 && idx < 8192)) {   // W1T [32][32], k permuted
            const float* W = (idx < 3072) ? m1_w1 : m0_w1;
            int r = (idx < 3072) ? idx - 2048 : idx - 7168;
            int o = r >> 5, p = r & 31;
            v = W[pinv(p)*32 + o];
        } else if (idx < 5120 || (idx >= 8192 && idx < 10240)) {  // W2T [64][32], k permuted, rows<40 scaled
            const float* W = (idx < 5120) ? m1_w2 : m0_w2;
            int r = (idx < 5120) ? idx - 3072 : idx - 8192;
            int o = r >> 5, p = r & 31;
            if (o < 59) {
                v = W[pinv(p)*59 + o];
                if (o < 40) v *= LOG2E;
            }
        } else {                                                  // p0 W0T [32][32], k logical
            int r = idx - 10240;
            int o = r >> 5, k = r & 31;
            if (k < 30) v = p0_w0[k*32 + o];
        }
        ws[idx] = (_Float16)v;
        return;
    }
    float* wsf = (float*)(ws + WS_F16);
    int bi = idx - WS_F16;
    if (bi < 288) {
        float v = 0.0f;
        if      (bi < 32)  v = m1_b0[bi];
        else if (bi < 64)  v = m1_b1[bi-32];
        else if (bi < 128) { int o = bi-64;  if (o < 59) { v = m1_b2[o]; if (o < 40) v *= LOG2E; } }
        else if (bi < 160) v = m0_b0[bi-128];
        else if (bi < 192) v = m0_b1[bi-160];
        else if (bi < 256) { int o = bi-192; if (o < 59) { v = m0_b2[o]; if (o < 40) v *= LOG2E; } }
        else               v = p0_b0[bi-256];
        wsf[bi] = v;
        return;
    }
    int pi = bi - 288;            // 0..63 : p0_w1 packed pairs
    int k2 = pi >> 2, j = pi & 3;
    union{ _Float16 h; unsigned short s; } a, b;
    a.h = (_Float16)p0_w1[(2*k2)*4 + j];
    b.h = (_Float16)p0_w1[(2*k2+1)*4 + j];
    ((u32*)(wsf + FB_PW1))[pi] = (u32)a.s | ((u32)b.s << 16);
}

// ---------- one transform MLP (noinline, emitted once), swapped-operand MFMA ----------
// Inter-layer activations stay IN REGISTERS (lane l's D-output == next-layer B-frag).
// Only L2's output goes to LDS (spline needs cross-lane gather).
__device__ __noinline__ void mlp_lds(int tid,
    const _Float16* __restrict__ W0, const _Float16* __restrict__ W1,
    const _Float16* __restrict__ W2,
    const float* __restrict__ B0p, const float* __restrict__ B1p,
    const float* __restrict__ B2p)
{
    _Float16* Sw = waveS() + (tid>>6)*4096;
    const int l = tid & 63, mrow = l & 15, g = (l >> 4) & 3;

    half8 hB[4];   // packed activations: physical 8g..8g+7 of point 16t+mrow

    // ---- L0: K=64 (2 ksteps), OUT=32; xin from LDS ----
    {
        half8 aW[2][2], bX[4][2];
#pragma unroll
        for (int n=0;n<2;++n)
#pragma unroll
            for (int s=0;s<2;++s)
                aW[n][s] = *(const half8*)(W0 + (16*n+mrow)*64 + 32*s + 8*g);
#pragma unroll
        for (int t=0;t<4;++t){
            int pt = 16*t + mrow;
#pragma unroll
            for (int s=0;s<2;++s) bX[t][s] = rd16(Sw, pt, 4*s+g);
        }
        float4v b0 = *(const float4v*)(B0p + 4*g);
        float4v b1 = *(const float4v*)(B0p + 16 + 4*g);
#pragma unroll
        for (int t=0;t<4;++t){
            float4v a0 = b0, a1 = b1;
            a0 = MFMA16(aW[0][0], bX[t][0], a0, 0,0,0);
            a0 = MFMA16(aW[0][1], bX[t][1], a0, 0,0,0);
            a1 = MFMA16(aW[1][0], bX[t][0], a1, 0,0,0);
            a1 = MFMA16(aW[1][1], bX[t][1], a1, 0,0,0);
            hB[t] = join8(pack4_lrelu(a0[0], a0[1], a0[2], a0[3]),
                          pack4_lrelu(a1[0], a1[1], a1[2], a1[3]));
        }
    }
    // ---- L1: K=32, OUT=32; B from regs, result back to regs (no LDS, no fence) ----
    {
        half8 aW[2];
#pragma unroll
        for (int n=0;n<2;++n) aW[n] = *(const half8*)(W1 + (16*n+mrow)*32 + 8*g);
        float4v b0 = *(const float4v*)(B1p + 4*g);
        float4v b1 = *(const float4v*)(B1p + 16 + 4*g);
#pragma unroll
        for (int t=0;t<4;++t){
            float4v a0 = b0, a1 = b1;
            a0 = MFMA16(aW[0], hB[t], a0, 0,0,0);
            a1 = MFMA16(aW[1], hB[t], a1, 0,0,0);
            hB[t] = join8(pack4_lrelu(a0[0], a0[1], a0[2], a0[3]),
                          pack4_lrelu(a1[0], a1[1], a1[2], a1[3]));
        }
    }
    // ---- L2: K=32, OUT=64 (59 real; outputs 0..39 pre-scaled by LOG2E); to LDS ----
    {
        half8 aW[4];
#pragma unroll
        for (int n=0;n<4;++n) aW[n] = *(const half8*)(W2 + (16*n+mrow)*32 + 8*g);
        float4v bb[4];
#pragma unroll
        for (int n=0;n<4;++n) bb[n] = *(const float4v*)(B2p + 16*n + 4*g);
#pragma unroll
        for (int t=0;t<4;++t){
            float4v a0=bb[0], a1=bb[1], a2=bb[2], a3=bb[3];
            a0 = MFMA16(aW[0], hB[t], a0, 0,0,0);
            a1 = MFMA16(aW[1], hB[t], a1, 0,0,0);
            a2 = MFMA16(aW[2], hB[t], a2, 0,0,0);
            a3 = MFMA16(aW[3], hB[t], a3, 0,0,0);
            int row = 16*t + mrow;
            wr16(Sw, row, 2*g,   join8(pack4(a0[0],a0[1],a0[2],a0[3]),
                                       pack4(a1[0],a1[1],a1[2],a1[3])));
            wr16(Sw, row, 2*g+1, join8(pack4(a2[0],a2[1],a2[2],a2[3]),
                                       pack4(a3[0],a3[1],a3[2],a3[3])));
        }
    }
    __threadfence_block();
}

// ---------- spline (noinline, emitted once) ----------
// uw/uh arrive pre-scaled by LOG2E -> exp2 direct, NO max subtraction.
// Single merged walk: both (cum,wv) and (hcum,hv) selected under u01>=cum.
__device__ __noinline__ float2 rqs_lds(float x, int tid)
{
    const int l = tid & 63;
    const int swz = l & 7;
    const _Float16* Sw = waveS() + (tid>>6)*4096;

    // widths+heights live in units {0,1,2,3,4,6}; derivs read dynamically below.
    half8 R[8];
    R[0]=rd16(Sw,l,0); R[1]=rd16(Sw,l,1); R[2]=rd16(Sw,l,2);
    R[3]=rd16(Sw,l,3); R[4]=rd16(Sw,l,4); R[6]=rd16(Sw,l,6);
    R[5]=R[4]; R[7]=R[6];   // dead (q never hits 5/7 for m<40); avoids UB

    float xc = fminf(fmaxf(x,-1.0f),1.0f);
    float u01 = fmaf(xc, 0.5f, 0.5f);       // walk in normalized cum-space

    float w[20], h[20];
#pragma unroll
    for (int i=0;i<20;++i){ int q = qpos(i);    w[i] = exp2fast((float)R[q>>3][q&7]); }
#pragma unroll
    for (int i=0;i<20;++i){ int q = qpos(20+i); h[i] = exp2fast((float)R[q>>3][q&7]); }
    float sw = 0.f, sh = 0.f;
#pragma unroll
    for (int i=0;i<20;++i){ sw += w[i]; sh += h[i]; }
    float invw = 0.98f / sw;
    float invh = 0.98f / sh;

    int idx = 0;
    float cumL = 0.0f, wvL = 1.0f, hcumL = 0.0f, hvL = 1.0f;
    float cum = 0.f, hcum = 0.f;
#pragma unroll
    for (int i=0;i<20;++i){
        float wv = fmaf(invw, w[i], 0.001f);
        float hv = fmaf(invh, h[i], 0.001f);
        if (u01 >= cum){ idx = i; cumL = cum; wvL = wv; hcumL = hcum; hvL = hv; }
        cum += wv; hcum += hv;
    }

    // derivs: udl = idx>0 ? tp[39+idx] : TAILC ; udr = idx<19 ? tp[40+idx] : TAILC
    auto rdq = [&](int m)->float{
        int q = 16*((m>>2)&3) + 8*((m>>4)>>1) + 4*((m>>4)&1) + (m&3);
        return (float)Sw[l*64 + (((q>>3) ^ swz)<<3) + (q&7)];
    };
    float dl = rdq(39+idx);
    float dr = rdq(40+idx);
    float udl = (idx>0)  ? dl : TAILC;
    float udr = (idx<19) ? dr : TAILC;

    float inD   = 0.001f + softplus_(udl);
    float inDp1 = 0.001f + softplus_(udr);
    float inDelta = hvL / wvL;              // (2hvL)/(2wvL)
    float inH  = 2.0f * hvL;
    float inCh = fmaf(2.0f, hcumL, -1.0f);
    float th  = (u01 - cumL) / wvL;         // == (xc - inCw)/inW
    float omt = 1.0f - th;
    float t1  = th * omt;
    float num = inH * (inDelta*th*th + inD*t1);
    float den = inDelta + (inD + inDp1 - 2.0f*inDelta)*t1;
    float y = inCh + num/den;
    float dnum = inDelta*inDelta*(inDp1*th*th + 2.0f*inDelta*t1 + inD*omt*omt);
    float lad = LN2 * (log2fast(dnum) - 2.0f*log2fast(den));
    bool inside = (x >= -1.0f) && (x <= 1.0f);
    return make_float2(inside ? y : x, inside ? lad : 0.0f);
}

__global__ __launch_bounds__(128,5) void nsf_mfma(
    const float* __restrict__ wi, const float* __restrict__ cond,
    const _Float16* __restrict__ wsp,
    const float* __restrict__ p0_b1,
    float* __restrict__ out)
{
    const int tid = threadIdx.x;
    const int l = tid & 63, wid = tid >> 6;
    const int i = blockIdx.x*128 + wid*64 + l;
    _Float16* Sw = waveS() + wid*4096;
    const int mrow = l & 15, g = (l >> 4) & 3;
    const float* wsf = (const float*)(wsp + WS_F16);

    float2 wv2 = reinterpret_cast<const float2*>(wi)[i];
    float w0v = wv2.x, w1v = wv2.y;
    float c[10];
    {
        const float2* cp2 = reinterpret_cast<const float2*>(cond + (size_t)i*10);
#pragma unroll
        for (int k=0;k<5;++k){ float2 t2 = cp2[k]; c[2*k]=t2.x; c[2*k+1]=t2.y; }
    }

    // cond_e -> f16 chunks A0..A3 (cols 0..31, incl. 2 zero pads)
    half8 A0, A1, A2, A3, Z;
#pragma unroll
    for (int j=0;j<8;++j) Z[j] = (_Float16)0.0f;
    {
        _Float16 ce[30];
        ce[0] = (_Float16)c[8];
        ce[1] = (_Float16)c[9];
        float f = 1.0f;
#pragma unroll
        for (int fi=0; fi<5; ++fi){
            float s8,c8v,s9,c9v;
            __sincosf(c[8]*f, &s8, &c8v);
            __sincosf(c[9]*f, &s9, &c9v);
            ce[2+4*fi+0]=(_Float16)s8;  ce[2+4*fi+1]=(_Float16)s9;
            ce[2+4*fi+2]=(_Float16)c8v; ce[2+4*fi+3]=(_Float16)c9v;
            f *= 2.0f;
        }
#pragma unroll
        for (int k=0;k<8;++k) ce[22+k] = (_Float16)c[k];
#pragma unroll
        for (int j=0;j<8;++j){ A0[j]=ce[j]; A1[j]=ce[8+j]; A2[j]=ce[16+j]; }
#pragma unroll
        for (int j=0;j<8;++j) A3[j] = (j<6) ? ce[24+j] : (_Float16)0.0f;
    }

    auto mkPE = [&](float t, half8& P0, half8& P1){
        float s1,c1v,s2,c2v,s3,c3v,s4,c4v;
        __sincosf(t*1.0f,       &s1,&c1v);
        __sincosf(t*3.3333333f, &s2,&c2v);
        __sincosf(t*5.6666665f, &s3,&c3v);
        __sincosf(t*8.0f,       &s4,&c4v);
        P0[0]=(_Float16)t;   P0[1]=(_Float16)s1; P0[2]=(_Float16)c1v; P0[3]=(_Float16)s2;
        P0[4]=(_Float16)c2v; P0[5]=(_Float16)s3; P0[6]=(_Float16)c3v; P0[7]=(_Float16)s4;
        P1 = Z; P1[0] = (_Float16)c4v;
    };

    // ---- m1: stage xin(w1v), MLP, spline on w0 ----
    half8 P0, P1;
    mkPE(w1v, P0, P1);
    wr16(Sw,l,0,A0); wr16(Sw,l,1,A1); wr16(Sw,l,2,A2); wr16(Sw,l,3,A3);
    wr16(Sw,l,4,P0); wr16(Sw,l,5,P1); wr16(Sw,l,6,Z);  wr16(Sw,l,7,Z);
    __threadfence_block();
    mlp_lds(tid, wsp+OFF_M1_W0T, wsp+OFF_M1_W1T, wsp+OFF_M1_W2T,
            wsf+FB_M1_B0, wsf+FB_M1_B1, wsf+FB_M1_B2);
    float2 r0 = rqs_lds(w0v, tid);
    float y0 = r0.x, ld0 = r0.y;

    // ---- m0: stage xin(y0), MLP, spline on w1 ----
    mkPE(y0, P0, P1);
    wr16(Sw,l,0,A0); wr16(Sw,l,1,A1); wr16(Sw,l,2,A2); wr16(Sw,l,3,A3);
    wr16(Sw,l,4,P0); wr16(Sw,l,5,P1); wr16(Sw,l,6,Z);  wr16(Sw,l,7,Z);
    __threadfence_block();
    mlp_lds(tid, wsp+OFF_M0_W0T, wsp+OFF_M0_W1T, wsp+OFF_M0_W2T,
            wsf+FB_M0_B0, wsf+FB_M0_B1, wsf+FB_M0_B2);
    float2 r1 = rqs_lds(w1v, tid);
    float y1 = r1.x, ld1 = r1.y;

    // ---- p0: cond_e(30,+2pad) -> 32 (lrelu) via swapped MFMA ----
    wr16(Sw,l,0,A0); wr16(Sw,l,1,A1); wr16(Sw,l,2,A2); wr16(Sw,l,3,A3);
    __threadfence_block();
    {
        half8 aW[2], bC[4];
#pragma unroll
        for (int n=0;n<2;++n) aW[n] = *(const half8*)(wsp + OFF_P0_W0T + (16*n+mrow)*32 + 8*g);
#pragma unroll
        for (int t=0;t<4;++t) bC[t] = rd16(Sw, 16*t+mrow, g);
        const float* PB = wsf + FB_P0_B0;
        float4v b0 = *(const float4v*)(PB + 4*g);
        float4v b1 = *(const float4v*)(PB + 16 + 4*g);
#pragma unroll
        for (int t=0;t<4;++t){
            float4v a0 = b0, a1 = b1;
            a0 = MFMA16(aW[0], bC[t], a0, 0,0,0);
            a1 = MFMA16(aW[1], bC[t], a1, 0,0,0);
            wr16(Sw, 16*t+mrow, g, join8(
                pack4_lrelu(a0[0], a0[1], a0[2], a0[3]),
                pack4_lrelu(a1[0], a1[1], a1[2], a1[3])));
        }
    }
    __threadfence_block();

    // ---- tail: per-thread 32 -> 4 via fdot2 (permuted unpack) ----
    float r4[4] = {p0_b1[0], p0_b1[1], p0_b1[2], p0_b1[3]};
    {
        half8 Tq[4];
#pragma unroll
        for (int u=0;u<4;++u) Tq[u] = rd16(Sw, l, u);
        const u32* pw = (const u32*)(wsf + FB_PW1);
#pragma unroll
        for (int k2=0;k2<16;++k2){
            int p = ppos(2*k2);                 // pair (2k2, 2k2+1) is position-adjacent
            h2 x; x[0] = Tq[p>>3][p&7]; x[1] = Tq[(p+1)>>3][(p+1)&7];
#pragma unroll
            for (int j=0;j<4;++j) r4[j] = fdot2(x, u2h2(pw[k2*4+j]), r4[j]);
        }
    }

    float mu0=r4[0], mu1=r4[1], ls0=r4[2], ls1=r4[3];
    float is0 = __expf(-ls0), is1 = __expf(-ls1);
    float e0 = (y0-mu0)*is0, e1 = (y1-mu1)*is1;
    float rr = e0*e0 + e1*e1;
    float lp = -(ls0+ls1) - 1.8378770664093453f - 0.5f*rr + ld0 + ld1;

    reinterpret_cast<float2*>(out)[i] = make_float2(y0, y1);
    out[2*(size_t)N_PTS + i] = lp;
}

// ---------------- fallback all-f32 kernel (known-good R1) ----------------
__device__ __forceinline__ float softplus_ref(float x){
    return fmaxf(x, 0.0f) + log1pf(__expf(-fabsf(x)));
}
__device__ __forceinline__ void rqs_f32(float x, float* tp, float& yo, float& lado)
{
    float mw = tp[0];
#pragma unroll
    for (int i=1;i<20;++i) mw = fmaxf(mw, tp[i]);
    float sw = 0.f;
#pragma unroll
    for (int i=0;i<20;++i){ tp[i] = __expf(tp[i]-mw); sw += tp[i]; }
    float invw = 0.98f / sw;
    float mh = tp[20];
#pragma unroll
    for (int i=1;i<20;++i) mh = fmaxf(mh, tp[20+i]);
    float sh = 0.f;
#pragma unroll
    for (int i=0;i<20;++i){ tp[20+i] = __expf(tp[20+i]-mh); sh += tp[20+i]; }
    float invh = 0.98f / sh;
    float xc = fminf(fmaxf(x,-1.0f),1.0f);
    float cum = 0.f; int idx = 0;
    float inCw = -1.0f, inW = 1.0f;
#pragma unroll
    for (int i=0;i<20;++i){
        float wv = fmaf(invw, tp[i], 0.001f);
        float cwL = (i==0) ? -1.0f : fmaf(2.0f, cum, -1.0f);
        float cumN = cum + wv;
        float cwR = (i==19) ? 1.0f : fmaf(2.0f, cumN, -1.0f);
        if (xc >= cwL){ idx = i; inCw = cwL; inW = cwR - cwL; }
        cum = cumN;
    }
    float hcum = 0.f; float inCh = -1.0f, inH = 1.0f;
#pragma unroll
    for (int i=0;i<20;++i){
        float hv = fmaf(invh, tp[20+i], 0.001f);
        float chL = (i==0) ? -1.0f : fmaf(2.0f, hcum, -1.0f);
        float hcumN = hcum + hv;
        float chR = (i==19) ? 1.0f : fmaf(2.0f, hcumN, -1.0f);
        if (i == idx){ inCh = chL; inH = chR - chL; }
        hcum = hcumN;
    }
    float udl = TAILC, udr = TAILC;
#pragma unroll
    for (int t=0;t<19;++t){
        if (idx == t+1) udl = tp[40+t];
        if (idx == t)   udr = tp[40+t];
    }
    float inD   = 0.001f + softplus_ref(udl);
    float inDp1 = 0.001f + softplus_ref(udr);
    float inDelta = inH / inW;
    float th  = (xc - inCw) / inW;
    float omt = 1.0f - th;
    float t1  = th * omt;
    float num = inH * (inDelta*th*th + inD*t1);
    float den = inDelta + (inD + inDp1 - 2.0f*inDelta)*t1;
    float y = inCh + num/den;
    float dnum = inDelta*inDelta*(inDp1*th*th + 2.0f*inDelta*t1 + inD*omt*omt);
    float lad = __logf(dnum) - 2.0f*__logf(den);
    bool inside = (x >= -1.0f) && (x <= 1.0f);
    yo   = inside ? y   : x;
    lado = inside ? lad : 0.0f;
}
template<int OUTW>
__device__ __forceinline__ void addrow(float v, const float* __restrict__ Wrow, float* acc){
#pragma unroll
    for (int j=0;j<OUTW;++j) acc[j] = fmaf(v, Wrow[j], acc[j]);
}
template<int KIN, int OUT>
__device__ __forceinline__ void dense(const float* x, const float* __restrict__ W,
        const float* __restrict__ B, float* acc){
#pragma unroll
    for (int j=0;j<OUT;++j) acc[j] = B[j];
#pragma unroll
    for (int k=0;k<KIN;++k){
#pragma unroll
        for (int j=0;j<OUT;++j) acc[j] = fmaf(x[k], W[k*OUT+j], acc[j]);
    }
}
__device__ __forceinline__ void mlp_layer0(float t, const float* c,
        const float* __restrict__ W0, const float* __restrict__ B0, float* h)
{
#pragma unroll
    for (int j=0;j<32;++j) h[j] = B0[j];
    addrow<32>(t, W0 + 0*32, h);
    float s, co;
    __sincosf(t*1.0f,       &s,&co); addrow<32>(s, W0+1*32, h); addrow<32>(co, W0+2*32, h);
    __sincosf(t*3.3333333f, &s,&co); addrow<32>(s, W0+3*32, h); addrow<32>(co, W0+4*32, h);
    __sincosf(t*5.6666665f, &s,&co); addrow<32>(s, W0+5*32, h); addrow<32>(co, W0+6*32, h);
    __sincosf(t*8.0f,       &s,&co); addrow<32>(s, W0+7*32, h); addrow<32>(co, W0+8*32, h);
    addrow<32>(c[8], W0 + 9*32, h);
    addrow<32>(c[9], W0 +10*32, h);
    float f = 1.0f;
#pragma unroll
    for (int fi=0; fi<5; ++fi){
        float s8,c8v,s9,c9v;
        __sincosf(c[8]*f, &s8, &c8v);
        __sincosf(c[9]*f, &s9, &c9v);
        addrow<32>(s8,  W0 + (11+4*fi)*32, h);
        addrow<32>(s9,  W0 + (12+4*fi)*32, h);
        addrow<32>(c8v, W0 + (13+4*fi)*32, h);
        addrow<32>(c9v, W0 + (14+4*fi)*32, h);
        f *= 2.0f;
    }
#pragma unroll
    for (int k=0;k<8;++k) addrow<32>(c[k], W0 + (31+k)*32, h);
#pragma unroll
    for (int j=0;j<32;++j) h[j] = lrelu(h[j]);
}
__global__ __launch_bounds__(256,3) void nsf_kernel_f32(
    const float* __restrict__ wi, const float* __restrict__ cond,
    const float* __restrict__ p0_w0, const float* __restrict__ p0_b0,
    const float* __restrict__ p0_w1, const float* __restrict__ p0_b1,
    const float* __restrict__ m1_w0, const float* __restrict__ m1_b0,
    const float* __restrict__ m1_w1, const float* __restrict__ m1_b1,
    const float* __restrict__ m1_w2, const float* __restrict__ m1_b2,
    const float* __restrict__ m0_w0, const float* __restrict__ m0_b0,
    const float* __restrict__ m0_w1, const float* __restrict__ m0_b1,
    const float* __restrict__ m0_w2, const float* __restrict__ m0_b2,
    float* __restrict__ out)
{
    const int i = blockIdx.x*256 + threadIdx.x;
    float2 wv2 = reinterpret_cast<const float2*>(wi)[i];
    float w0v = wv2.x, w1v = wv2.y;
    const float* cp = cond + (size_t)i*10;
    float c[10];
#pragma unroll
    for (int k=0;k<10;++k) c[k] = cp[k];

    float tp[59];
    {
        float h[32], gg[32];
        mlp_layer0(w1v, c, m1_w0, m1_b0, h);
        dense<32,32>(h, m1_w1, m1_b1, gg);
#pragma unroll
        for (int j=0;j<32;++j) gg[j] = lrelu(gg[j]);
        dense<32,59>(gg, m1_w2, m1_b2, tp);
    }
    float y0, ld0; rqs_f32(w0v, tp, y0, ld0);
    {
        float h[32], gg[32];
        mlp_layer0(y0, c, m0_w0, m0_b0, h);
        dense<32,32>(h, m0_w1, m0_b1, gg);
#pragma unroll
        for (int j=0;j<32;++j) gg[j] = lrelu(gg[j]);
        dense<32,59>(gg, m0_w2, m0_b2, tp);
    }
    float y1, ld1; rqs_f32(w1v, tp, y1, ld1);

    float r[4];
    {
        float ph[32];
#pragma unroll
        for (int j=0;j<32;++j) ph[j] = p0_b0[j];
        addrow<32>(c[8], p0_w0 + 0*32, ph);
        addrow<32>(c[9], p0_w0 + 1*32, ph);
        float f = 1.0f;
#pragma unroll
        for (int fi=0; fi<5; ++fi){
            float s8,c8v,s9,c9v;
            __sincosf(c[8]*f, &s8, &c8v);
            __sincosf(c[9]*f, &s9, &c9v);
            addrow<32>(s8,  p0_w0 + (2+4*fi)*32, ph);
            addrow<32>(s9,  p0_w0 + (3+4*fi)*32, ph);
            addrow<32>(c8v, p0_w0 + (4+4*fi)*32, ph);
            addrow<32>(c9v, p0_w0 + (5+4*fi)*32, ph);
            f *= 2.0f;
        }
#pragma unroll
        for (int k=0;k<8;++k) addrow<32>(c[k], p0_w0 + (22+k)*32, ph);
#pragma unroll
        for (int j=0;j<32;++j) ph[j] = lrelu(ph[j]);
        dense<32,4>(ph, p0_w1, p0_b1, r);
    }

    float mu0=r[0], mu1=r[1], ls0=r[2], ls1=r[3];
    float is0 = __expf(-ls0), is1 = __expf(-ls1);
    float e0 = (y0-mu0)*is0, e1 = (y1-mu1)*is1;
    float rr = e0*e0 + e1*e1;
    float lp = -(ls0+ls1) - 1.8378770664093453f - 0.5f*rr + ld0 + ld1;

    reinterpret_cast<float2*>(out)[i] = make_float2(y0, y1);
    out[2*(size_t)N_PTS + i] = lp;
}

extern "C" void kernel_launch(void* const* d_in, const int* in_sizes, int n_in,
                              void* d_out, int out_size, void* d_ws, size_t ws_size,
                              hipStream_t stream)
{
    const float* wi    = (const float*)d_in[0];
    const float* cond  = (const float*)d_in[1];
    const float* p0_w0 = (const float*)d_in[2];
    const float* p0_b0 = (const float*)d_in[3];
    const float* p0_w1 = (const float*)d_in[4];
    const float* p0_b1 = (const float*)d_in[5];
    const float* m1_w0 = (const float*)d_in[6];
    const float* m1_b0 = (const float*)d_in[7];
    const float* m1_w1 = (const float*)d_in[8];
    const float* m1_b1 = (const float*)d_in[9];
    const float* m1_w2 = (const float*)d_in[10];
    const float* m1_b2 = (const float*)d_in[11];
    const float* m0_w0 = (const float*)d_in[12];
    const float* m0_b0 = (const float*)d_in[13];
    const float* m0_w1 = (const float*)d_in[14];
    const float* m0_b1 = (const float*)d_in[15];
    const float* m0_w2 = (const float*)d_in[16];
    const float* m0_b2 = (const float*)d_in[17];
    float* out = (float*)d_out;

    if (ws_size >= (size_t)WS_BYTES) {
        _Float16* wsp = (_Float16*)d_ws;
        hipLaunchKernelGGL(pack_weights, dim3((PACK_ITEMS+255)/256), dim3(256), 0, stream,
            m1_w0, m1_w1, m1_w2, m0_w0, m0_w1, m0_w2, p0_w0, p0_w1,
            m1_b0, m1_b1, m1_b2, m0_b0, m0_b1, m0_b2, p0_b0, wsp);
        hipLaunchKernelGGL(nsf_mfma, dim3(N_PTS/128), dim3(128), 0, stream,
            wi, cond, wsp, p0_b1, out);
    } else {
        hipLaunchKernelGGL(nsf_kernel_f32, dim3(N_PTS/256), dim3(256), 0, stream,
            wi, cond, p0_w0, p0_b0, p0_w1, p0_b1,
            m1_w0, m1_b0, m1_w1, m1_b1, m1_w2, m1_b2,
            m0_w0, m0_b0, m0_w1, m0_b1, m0_w2, m0_b2, out);
    }
}

// Round 15
// 147.298 us; speedup vs baseline: 1.0328x; 1.0328x over previous
//
#include <hip/hip_runtime.h>
#include <math.h>

#define N_PTS 2097152
#define TAILC 0.53974324f   // log(exp(1-0.001)-1)
#define LOG2E 1.4426950408889634f
#define LN2   0.6931471805599453f

typedef unsigned int u32;
typedef _Float16 half8 __attribute__((ext_vector_type(8)));
typedef _Float16 half4 __attribute__((ext_vector_type(4)));
typedef _Float16 h2    __attribute__((ext_vector_type(2)));
typedef __fp16   fp16x2 __attribute__((ext_vector_type(2)));
typedef float float4v  __attribute__((ext_vector_type(4)));

#define MFMA16 __builtin_amdgcn_mfma_f32_16x16x32_f16

__device__ __forceinline__ float lrelu(float x){ return x > 0.0f ? x : 0.01f*x; }
__device__ __forceinline__ float exp2fast(float x){
#if __has_builtin(__builtin_amdgcn_exp2f)
    return __builtin_amdgcn_exp2f(x);
#else
    return exp2f(x);
#endif
}
__device__ __forceinline__ float log2fast(float x){
#if __has_builtin(__builtin_amdgcn_logf)
    return __builtin_amdgcn_logf(x);
#else
    return __log2f(x);
#endif
}
// softplus(x) = ln2 * log2(1 + exp2(x*log2e)); f32-safe for |x| < ~80
__device__ __forceinline__ float softplus_(float x){
    return LN2 * log2fast(1.0f + exp2fast(x * LOG2E));
}
__device__ __forceinline__ half4 pack4(float a0, float a1, float a2, float a3){
#if __has_builtin(__builtin_amdgcn_cvt_pkrtz)
    union { fp16x2 f; h2 h; } lo, hi;
    lo.f = __builtin_amdgcn_cvt_pkrtz(a0, a1);
    hi.f = __builtin_amdgcn_cvt_pkrtz(a2, a3);
    half4 r; r[0]=lo.h[0]; r[1]=lo.h[1]; r[2]=hi.h[0]; r[3]=hi.h[1];
    return r;
#else
    half4 r; r[0]=(_Float16)a0; r[1]=(_Float16)a1; r[2]=(_Float16)a2; r[3]=(_Float16)a3;
    return r;
#endif
}
// packed f16 leaky-relu: v_pk_mul_f16 + v_pk_max_f16 via elementwise builtins
__device__ __forceinline__ h2 lrelu2(h2 x){
#if __has_builtin(__builtin_elementwise_max)
    h2 m = x * (_Float16)0.01f;
    return __builtin_elementwise_max(x, m);
#else
    h2 r; r[0] = (x[0] > (_Float16)0 ? x[0] : x[0]*(_Float16)0.01f);
    r[1] = (x[1] > (_Float16)0 ? x[1] : x[1]*(_Float16)0.01f);
    return r;
#endif
}
// pack 4 f32 -> 4 f16 then leaky-relu in PACKED f16
__device__ __forceinline__ half4 pack4_lrelu(float a0, float a1, float a2, float a3){
#if __has_builtin(__builtin_amdgcn_cvt_pkrtz)
    union { fp16x2 f; h2 h; } lo, hi;
    lo.f = __builtin_amdgcn_cvt_pkrtz(a0, a1);
    hi.f = __builtin_amdgcn_cvt_pkrtz(a2, a3);
    h2 lm = lrelu2(lo.h), hm = lrelu2(hi.h);
    half4 r; r[0]=lm[0]; r[1]=lm[1]; r[2]=hm[0]; r[3]=hm[1];
    return r;
#else
    return pack4(lrelu(a0), lrelu(a1), lrelu(a2), lrelu(a3));
#endif
}
__device__ __forceinline__ half8 join8(half4 a, half4 b){
    half8 r; r[0]=a[0]; r[1]=a[1]; r[2]=a[2]; r[3]=a[3];
    r[4]=b[0]; r[5]=b[1]; r[6]=b[2]; r[7]=b[3];
    return r;
}
__device__ __forceinline__ float fdot2(h2 a, h2 b, float c){
#if __has_builtin(__builtin_amdgcn_fdot2)
    return __builtin_amdgcn_fdot2(a, b, c, false);
#else
    return fmaf((float)a[0],(float)b[0], fmaf((float)a[1],(float)b[1], c));
#endif
}
__device__ __forceinline__ h2 u2h2(u32 u){ union{u32 a; h2 b;} x; x.a=u; return x.b; }

// physical position of logical output o for 32-wide layers (p = 8g + 4n + j, o = 16n+4g+j)
__device__ __host__ constexpr int ppos(int o){
    return 8*((o>>2)&3) + 4*(o>>4) + (o&3);
}
// physical position of logical output m for the 64-wide L2 layer
__device__ __host__ constexpr int qpos(int m){
    return 16*((m>>2)&3) + 8*((m>>4)>>1) + 4*((m>>4)&1) + (m&3);
}
// inverse: logical o at physical p (32-wide)
__device__ __host__ constexpr int pinv(int p){
    return 16*((p>>2)&1) + 4*(p>>3) + (p&3);
}

// Single shared allocation reachable from kernel AND noinline callees.
// 4 waves per 256-thread block, 32KB/block -> 5 blocks/CU = 20 waves (62.5%).
__device__ __forceinline__ _Float16* waveS(){
    __shared__ _Float16 S[4][4096];    // per-wave [64 rows][64 f16], swizzled
    return &S[0][0];
}
__device__ __forceinline__ half8 rd16(const _Float16* Sw, int row, int u){
    return *(const half8*)(Sw + row*64 + ((u ^ (row&7))<<3));
}
__device__ __forceinline__ void wr16(_Float16* Sw, int row, int u, half8 v){
    *(half8*)(Sw + row*64 + ((u ^ (row&7))<<3)) = v;
}

// ---- packed weights/biases in d_ws ----
#define OFF_M1_W0T 0        // [32][64]
#define OFF_M1_W1T 2048     // [32][32]
#define OFF_M1_W2T 3072     // [64][32]
#define OFF_M0_W0T 5120
#define OFF_M0_W1T 7168
#define OFF_M0_W2T 8192
#define OFF_P0_W0T 10240    // [32][32]
#define WS_F16     11264
// f32 region (byte 22528)
#define FB_M1_B0   0
#define FB_M1_B1   32
#define FB_M1_B2   64       // padded to 64, outputs 0..39 pre-scaled by LOG2E
#define FB_M0_B0   128
#define FB_M0_B1   160
#define FB_M0_B2   192
#define FB_P0_B0   256
#define FB_PW1     288      // 64 u32: p0_w1 packed h2 pairs
#define WS_BYTES   (22528 + 288*4 + 64*4)
#define PACK_ITEMS (WS_F16 + 288 + 64)

__global__ void pack_weights(const float* __restrict__ m1_w0, const float* __restrict__ m1_w1,
                             const float* __restrict__ m1_w2, const float* __restrict__ m0_w0,
                             const float* __restrict__ m0_w1, const float* __restrict__ m0_w2,
                             const float* __restrict__ p0_w0, const float* __restrict__ p0_w1,
                             const float* __restrict__ m1_b0, const float* __restrict__ m1_b1,
                             const float* __restrict__ m1_b2, const float* __restrict__ m0_b0,
                             const float* __restrict__ m0_b1, const float* __restrict__ m0_b2,
                             const float* __restrict__ p0_b0, _Float16* __restrict__ ws)
{
    int idx = blockIdx.x*256 + threadIdx.x;
    if (idx >= PACK_ITEMS) return;
    if (idx < WS_F16) {
        float v = 0.0f;
        if (idx < 2048 || (idx >= 5120 && idx < 7168)) {          // W0T [32][64], k logical
            const float* W = (idx < 2048) ? m1_w0 : m0_w0;
            int r = (idx < 2048) ? idx : idx - 5120;
            int o = r >> 6, k = r & 63;
            if (k < 30)                 v = W[(9+k)*32 + o];
            else if (k >= 32 && k < 41) v = W[(k-32)*32 + o];
        } else if (idx < 3072 || (idx >= 7168 && idx < 8192)) {   // W1T [32][32], k permuted
            const float* W = (idx < 3072) ? m1_w1 : m0_w1;
            int r = (idx < 3072) ? idx - 2048 : idx - 7168;
            int o = r >> 5, p = r & 31;
            v = W[pinv(p)*32 + o];
        } else if (idx < 5120 || (idx >= 8192 && idx < 10240)) {  // W2T [64][32], k permuted, rows<40 scaled
            const float* W = (idx < 5120) ? m1_w2 : m0_w2;
            int r = (idx < 5120) ? idx - 3072 : idx - 8192;
            int o = r >> 5, p = r & 31;
            if (o < 59) {
                v = W[pinv(p)*59 + o];
                if (o < 40) v *= LOG2E;
            }
        } else {                                                  // p0 W0T [32][32], k logical
            int r = idx - 10240;
            int o = r >> 5, k = r & 31;
            if (k < 30) v = p0_w0[k*32 + o];
        }
        ws[idx] = (_Float16)v;
        return;
    }
    float* wsf = (float*)(ws + WS_F16);
    int bi = idx - WS_F16;
    if (bi < 288) {
        float v = 0.0f;
        if      (bi < 32)  v = m1_b0[bi];
        else if (bi < 64)  v = m1_b1[bi-32];
        else if (bi < 128) { int o = bi-64;  if (o < 59) { v = m1_b2[o]; if (o < 40) v *= LOG2E; } }
        else if (bi < 160) v = m0_b0[bi-128];
        else if (bi < 192) v = m0_b1[bi-160];
        else if (bi < 256) { int o = bi-192; if (o < 59) { v = m0_b2[o]; if (o < 40) v *= LOG2E; } }
        else               v = p0_b0[bi-256];
        wsf[bi] = v;
        return;
    }
    int pi = bi - 288;            // 0..63 : p0_w1 packed pairs
    int k2 = pi >> 2, j = pi & 3;
    union{ _Float16 h; unsigned short s; } a, b;
    a.h = (_Float16)p0_w1[(2*k2)*4 + j];
    b.h = (_Float16)p0_w1[(2*k2+1)*4 + j];
    ((u32*)(wsf + FB_PW1))[pi] = (u32)a.s | ((u32)b.s << 16);
}

// ---------- one transform MLP (noinline, emitted once), swapped-operand MFMA ----------
// Inter-layer activations stay IN REGISTERS (lane l's D-output == next-layer B-frag).
// Only L2's output goes to LDS (spline needs cross-lane gather).
__device__ __noinline__ void mlp_lds(int tid,
    const _Float16* __restrict__ W0, const _Float16* __restrict__ W1,
    const _Float16* __restrict__ W2,
    const float* __restrict__ B0p, const float* __restrict__ B1p,
    const float* __restrict__ B2p)
{
    _Float16* Sw = waveS() + (tid>>6)*4096;
    const int l = tid & 63, mrow = l & 15, g = (l >> 4) & 3;

    half8 hB[4];   // packed activations: physical 8g..8g+7 of point 16t+mrow

    // ---- L0: K=64 (2 ksteps), OUT=32; xin from LDS ----
    {
        half8 aW[2][2], bX[4][2];
#pragma unroll
        for (int n=0;n<2;++n)
#pragma unroll
            for (int s=0;s<2;++s)
                aW[n][s] = *(const half8*)(W0 + (16*n+mrow)*64 + 32*s + 8*g);
#pragma unroll
        for (int t=0;t<4;++t){
            int pt = 16*t + mrow;
#pragma unroll
            for (int s=0;s<2;++s) bX[t][s] = rd16(Sw, pt, 4*s+g);
        }
        float4v b0 = *(const float4v*)(B0p + 4*g);
        float4v b1 = *(const float4v*)(B0p + 16 + 4*g);
#pragma unroll
        for (int t=0;t<4;++t){
            float4v a0 = b0, a1 = b1;
            a0 = MFMA16(aW[0][0], bX[t][0], a0, 0,0,0);
            a0 = MFMA16(aW[0][1], bX[t][1], a0, 0,0,0);
            a1 = MFMA16(aW[1][0], bX[t][0], a1, 0,0,0);
            a1 = MFMA16(aW[1][1], bX[t][1], a1, 0,0,0);
            hB[t] = join8(pack4_lrelu(a0[0], a0[1], a0[2], a0[3]),
                          pack4_lrelu(a1[0], a1[1], a1[2], a1[3]));
        }
    }
    // ---- L1: K=32, OUT=32; B from regs, result back to regs (no LDS, no fence) ----
    {
        half8 aW[2];
#pragma unroll
        for (int n=0;n<2;++n) aW[n] = *(const half8*)(W1 + (16*n+mrow)*32 + 8*g);
        float4v b0 = *(const float4v*)(B1p + 4*g);
        float4v b1 = *(const float4v*)(B1p + 16 + 4*g);
#pragma unroll
        for (int t=0;t<4;++t){
            float4v a0 = b0, a1 = b1;
            a0 = MFMA16(aW[0], hB[t], a0, 0,0,0);
            a1 = MFMA16(aW[1], hB[t], a1, 0,0,0);
            hB[t] = join8(pack4_lrelu(a0[0], a0[1], a0[2], a0[3]),
                          pack4_lrelu(a1[0], a1[1], a1[2], a1[3]));
        }
    }
    // ---- L2: K=32, OUT=64 (59 real; outputs 0..39 pre-scaled by LOG2E); to LDS ----
    {
        half8 aW[4];
#pragma unroll
        for (int n=0;n<4;++n) aW[n] = *(const half8*)(W2 + (16*n+mrow)*32 + 8*g);
        float4v bb[4];
#pragma unroll
        for (int n=0;n<4;++n) bb[n] = *(const float4v*)(B2p + 16*n + 4*g);
#pragma unroll
        for (int t=0;t<4;++t){
            float4v a0=bb[0], a1=bb[1], a2=bb[2], a3=bb[3];
            a0 = MFMA16(aW[0], hB[t], a0, 0,0,0);
            a1 = MFMA16(aW[1], hB[t], a1, 0,0,0);
            a2 = MFMA16(aW[2], hB[t], a2, 0,0,0);
            a3 = MFMA16(aW[3], hB[t], a3, 0,0,0);
            int row = 16*t + mrow;
            wr16(Sw, row, 2*g,   join8(pack4(a0[0],a0[1],a0[2],a0[3]),
                                       pack4(a1[0],a1[1],a1[2],a1[3])));
            wr16(Sw, row, 2*g+1, join8(pack4(a2[0],a2[1],a2[2],a2[3]),
                                       pack4(a3[0],a3[1],a3[2],a3[3])));
        }
    }
    __threadfence_block();
}

// ---------- spline (noinline, emitted once), REGISTER-LEAN ----------
// uw/uh arrive pre-scaled by LOG2E -> exp2 direct, NO max subtraction.
// No f32 w[20]/h[20] arrays: pass 1 sums exp2 on the fly from packed R[];
// the walk recomputes exp2 per bin (serial cum chain hides the recompute).
__device__ __noinline__ float2 rqs_lds(float x, int tid)
{
    const int l = tid & 63;
    const int swz = l & 7;
    const _Float16* Sw = waveS() + (tid>>6)*4096;

    // widths+heights live in units {0,1,2,3,4,6}; derivs read dynamically below.
    half8 R[8];
    R[0]=rd16(Sw,l,0); R[1]=rd16(Sw,l,1); R[2]=rd16(Sw,l,2);
    R[3]=rd16(Sw,l,3); R[4]=rd16(Sw,l,4); R[6]=rd16(Sw,l,6);
    R[5]=R[4]; R[7]=R[6];   // dead (q never hits 5/7 for m<40); avoids UB

    float xc = fminf(fmaxf(x,-1.0f),1.0f);
    float u01 = fmaf(xc, 0.5f, 0.5f);       // walk in normalized cum-space

    // pass 1: softmax denominators (streaming, no arrays)
    float sw = 0.f, sh = 0.f;
#pragma unroll
    for (int i=0;i<20;++i){
        int qw = qpos(i), qh = qpos(20+i);
        sw += exp2fast((float)R[qw>>3][qw&7]);
        sh += exp2fast((float)R[qh>>3][qh&7]);
    }
    float invw = 0.98f / sw;
    float invh = 0.98f / sh;

    // pass 2: merged walk; recompute exp2 per bin
    int idx = 0;
    float cumL = 0.0f, wvL = 1.0f, hcumL = 0.0f, hvL = 1.0f;
    float cum = 0.f, hcum = 0.f;
#pragma unroll
    for (int i=0;i<20;++i){
        int qw = qpos(i), qh = qpos(20+i);
        float wv = fmaf(invw, exp2fast((float)R[qw>>3][qw&7]), 0.001f);
        float hv = fmaf(invh, exp2fast((float)R[qh>>3][qh&7]), 0.001f);
        if (u01 >= cum){ idx = i; cumL = cum; wvL = wv; hcumL = hcum; hvL = hv; }
        cum += wv; hcum += hv;
    }

    // derivs: udl = idx>0 ? tp[39+idx] : TAILC ; udr = idx<19 ? tp[40+idx] : TAILC
    auto rdq = [&](int m)->float{
        int q = 16*((m>>2)&3) + 8*((m>>4)>>1) + 4*((m>>4)&1) + (m&3);
        return (float)Sw[l*64 + (((q>>3) ^ swz)<<3) + (q&7)];
    };
    float dl = rdq(39+idx);
    float dr = rdq(40+idx);
    float udl = (idx>0)  ? dl : TAILC;
    float udr = (idx<19) ? dr : TAILC;

    float inD   = 0.001f + softplus_(udl);
    float inDp1 = 0.001f + softplus_(udr);
    float inDelta = hvL / wvL;              // (2hvL)/(2wvL)
    float inH  = 2.0f * hvL;
    float inCh = fmaf(2.0f, hcumL, -1.0f);
    float th  = (u01 - cumL) / wvL;         // == (xc - inCw)/inW
    float omt = 1.0f - th;
    float t1  = th * omt;
    float num = inH * (inDelta*th*th + inD*t1);
    float den = inDelta + (inD + inDp1 - 2.0f*inDelta)*t1;
    float y = inCh + num/den;
    float dnum = inDelta*inDelta*(inDp1*th*th + 2.0f*inDelta*t1 + inD*omt*omt);
    float lad = LN2 * (log2fast(dnum) - 2.0f*log2fast(den));
    bool inside = (x >= -1.0f) && (x <= 1.0f);
    return make_float2(inside ? y : x, inside ? lad : 0.0f);
}

__global__ __launch_bounds__(256,5) void nsf_mfma(
    const float* __restrict__ wi, const float* __restrict__ cond,
    const _Float16* __restrict__ wsp,
    const float* __restrict__ p0_b1,
    float* __restrict__ out)
{
    const int tid = threadIdx.x;
    const int l = tid & 63, wid = tid >> 6;
    const int i = blockIdx.x*256 + wid*64 + l;
    _Float16* Sw = waveS() + wid*4096;
    const int mrow = l & 15, g = (l >> 4) & 3;
    const float* wsf = (const float*)(wsp + WS_F16);

    float2 wv2 = reinterpret_cast<const float2*>(wi)[i];
    float w0v = wv2.x, w1v = wv2.y;
    float c[10];
    {
        const float2* cp2 = reinterpret_cast<const float2*>(cond + (size_t)i*10);
#pragma unroll
        for (int k=0;k<5;++k){ float2 t2 = cp2[k]; c[2*k]=t2.x; c[2*k+1]=t2.y; }
    }

    // cond_e -> f16 chunks A0..A3 (cols 0..31, incl. 2 zero pads)
    half8 A0, A1, A2, A3, Z;
#pragma unroll
    for (int j=0;j<8;++j) Z[j] = (_Float16)0.0f;
    {
        _Float16 ce[30];
        ce[0] = (_Float16)c[8];
        ce[1] = (_Float16)c[9];
        float f = 1.0f;
#pragma unroll
        for (int fi=0; fi<5; ++fi){
            float s8,c8v,s9,c9v;
            __sincosf(c[8]*f, &s8, &c8v);
            __sincosf(c[9]*f, &s9, &c9v);
            ce[2+4*fi+0]=(_Float16)s8;  ce[2+4*fi+1]=(_Float16)s9;
            ce[2+4*fi+2]=(_Float16)c8v; ce[2+4*fi+3]=(_Float16)c9v;
            f *= 2.0f;
        }
#pragma unroll
        for (int k=0;k<8;++k) ce[22+k] = (_Float16)c[k];
#pragma unroll
        for (int j=0;j<8;++j){ A0[j]=ce[j]; A1[j]=ce[8+j]; A2[j]=ce[16+j]; }
#pragma unroll
        for (int j=0;j<8;++j) A3[j] = (j<6) ? ce[24+j] : (_Float16)0.0f;
    }

    auto mkPE = [&](float t, half8& P0, half8& P1){
        float s1,c1v,s2,c2v,s3,c3v,s4,c4v;
        __sincosf(t*1.0f,       &s1,&c1v);
        __sincosf(t*3.3333333f, &s2,&c2v);
        __sincosf(t*5.6666665f, &s3,&c3v);
        __sincosf(t*8.0f,       &s4,&c4v);
        P0[0]=(_Float16)t;   P0[1]=(_Float16)s1; P0[2]=(_Float16)c1v; P0[3]=(_Float16)s2;
        P0[4]=(_Float16)c2v; P0[5]=(_Float16)s3; P0[6]=(_Float16)c3v; P0[7]=(_Float16)s4;
        P1 = Z; P1[0] = (_Float16)c4v;
    };

    // ---- m1: stage xin(w1v), MLP, spline on w0 ----
    half8 P0, P1;
    mkPE(w1v, P0, P1);
    wr16(Sw,l,0,A0); wr16(Sw,l,1,A1); wr16(Sw,l,2,A2); wr16(Sw,l,3,A3);
    wr16(Sw,l,4,P0); wr16(Sw,l,5,P1); wr16(Sw,l,6,Z);  wr16(Sw,l,7,Z);
    __threadfence_block();
    mlp_lds(tid, wsp+OFF_M1_W0T, wsp+OFF_M1_W1T, wsp+OFF_M1_W2T,
            wsf+FB_M1_B0, wsf+FB_M1_B1, wsf+FB_M1_B2);
    float2 r0 = rqs_lds(w0v, tid);
    float y0 = r0.x, ld0 = r0.y;

    // ---- m0: stage xin(y0), MLP, spline on w1 ----
    mkPE(y0, P0, P1);
    wr16(Sw,l,0,A0); wr16(Sw,l,1,A1); wr16(Sw,l,2,A2); wr16(Sw,l,3,A3);
    wr16(Sw,l,4,P0); wr16(Sw,l,5,P1); wr16(Sw,l,6,Z);  wr16(Sw,l,7,Z);
    __threadfence_block();
    mlp_lds(tid, wsp+OFF_M0_W0T, wsp+OFF_M0_W1T, wsp+OFF_M0_W2T,
            wsf+FB_M0_B0, wsf+FB_M0_B1, wsf+FB_M0_B2);
    float2 r1 = rqs_lds(w1v, tid);
    float y1 = r1.x, ld1 = r1.y;

    // ---- p0: cond_e(30,+2pad) -> 32 (lrelu) via swapped MFMA ----
    wr16(Sw,l,0,A0); wr16(Sw,l,1,A1); wr16(Sw,l,2,A2); wr16(Sw,l,3,A3);
    __threadfence_block();
    {
        half8 aW[2], bC[4];
#pragma unroll
        for (int n=0;n<2;++n) aW[n] = *(const half8*)(wsp + OFF_P0_W0T + (16*n+mrow)*32 + 8*g);
#pragma unroll
        for (int t=0;t<4;++t) bC[t] = rd16(Sw, 16*t+mrow, g);
        const float* PB = wsf + FB_P0_B0;
        float4v b0 = *(const float4v*)(PB + 4*g);
        float4v b1 = *(const float4v*)(PB + 16 + 4*g);
#pragma unroll
        for (int t=0;t<4;++t){
            float4v a0 = b0, a1 = b1;
            a0 = MFMA16(aW[0], bC[t], a0, 0,0,0);
            a1 = MFMA16(aW[1], bC[t], a1, 0,0,0);
            wr16(Sw, 16*t+mrow, g, join8(
                pack4_lrelu(a0[0], a0[1], a0[2], a0[3]),
                pack4_lrelu(a1[0], a1[1], a1[2], a1[3])));
        }
    }
    __threadfence_block();

    // ---- tail: per-thread 32 -> 4 via fdot2 (permuted unpack) ----
    float r4[4] = {p0_b1[0], p0_b1[1], p0_b1[2], p0_b1[3]};
    {
        half8 Tq[4];
#pragma unroll
        for (int u=0;u<4;++u) Tq[u] = rd16(Sw, l, u);
        const u32* pw = (const u32*)(wsf + FB_PW1);
#pragma unroll
        for (int k2=0;k2<16;++k2){
            int p = ppos(2*k2);                 // pair (2k2, 2k2+1) is position-adjacent
            h2 x; x[0] = Tq[p>>3][p&7]; x[1] = Tq[(p+1)>>3][(p+1)&7];
#pragma unroll
            for (int j=0;j<4;++j) r4[j] = fdot2(x, u2h2(pw[k2*4+j]), r4[j]);
        }
    }

    float mu0=r4[0], mu1=r4[1], ls0=r4[2], ls1=r4[3];
    float is0 = __expf(-ls0), is1 = __expf(-ls1);
    float e0 = (y0-mu0)*is0, e1 = (y1-mu1)*is1;
    float rr = e0*e0 + e1*e1;
    float lp = -(ls0+ls1) - 1.8378770664093453f - 0.5f*rr + ld0 + ld1;

    reinterpret_cast<float2*>(out)[i] = make_float2(y0, y1);
    out[2*(size_t)N_PTS + i] = lp;
}

// ---------------- fallback all-f32 kernel (known-good R1) ----------------
__device__ __forceinline__ float softplus_ref(float x){
    return fmaxf(x, 0.0f) + log1pf(__expf(-fabsf(x)));
}
__device__ __forceinline__ void rqs_f32(float x, float* tp, float& yo, float& lado)
{
    float mw = tp[0];
#pragma unroll
    for (int i=1;i<20;++i) mw = fmaxf(mw, tp[i]);
    float sw = 0.f;
#pragma unroll
    for (int i=0;i<20;++i){ tp[i] = __expf(tp[i]-mw); sw += tp[i]; }
    float invw = 0.98f / sw;
    float mh = tp[20];
#pragma unroll
    for (int i=1;i<20;++i) mh = fmaxf(mh, tp[20+i]);
    float sh = 0.f;
#pragma unroll
    for (int i=0;i<20;++i){ tp[20+i] = __expf(tp[20+i]-mh); sh += tp[20+i]; }
    float invh = 0.98f / sh;
    float xc = fminf(fmaxf(x,-1.0f),1.0f);
    float cum = 0.f; int idx = 0;
    float inCw = -1.0f, inW = 1.0f;
#pragma unroll
    for (int i=0;i<20;++i){
        float wv = fmaf(invw, tp[i], 0.001f);
        float cwL = (i==0) ? -1.0f : fmaf(2.0f, cum, -1.0f);
        float cumN = cum + wv;
        float cwR = (i==19) ? 1.0f : fmaf(2.0f, cumN, -1.0f);
        if (xc >= cwL){ idx = i; inCw = cwL; inW = cwR - cwL; }
        cum = cumN;
    }
    float hcum = 0.f; float inCh = -1.0f, inH = 1.0f;
#pragma unroll
    for (int i=0;i<20;++i){
        float hv = fmaf(invh, tp[20+i], 0.001f);
        float chL = (i==0) ? -1.0f : fmaf(2.0f, hcum, -1.0f);
        float hcumN = hcum + hv;
        float chR = (i==19) ? 1.0f : fmaf(2.0f, hcumN, -1.0f);
        if (i == idx){ inCh = chL; inH = chR - chL; }
        hcum = hcumN;
    }
    float udl = TAILC, udr = TAILC;
#pragma unroll
    for (int t=0;t<19;++t){
        if (idx == t+1) udl = tp[40+t];
        if (idx == t)   udr = tp[40+t];
    }
    float inD   = 0.001f + softplus_ref(udl);
    float inDp1 = 0.001f + softplus_ref(udr);
    float inDelta = inH / inW;
    float th  = (xc - inCw) / inW;
    float omt = 1.0f - th;
    float t1  = th * omt;
    float num = inH * (inDelta*th*th + inD*t1);
    float den = inDelta + (inD + inDp1 - 2.0f*inDelta)*t1;
    float y = inCh + num/den;
    float dnum = inDelta*inDelta*(inDp1*th*th + 2.0f*inDelta*t1 + inD*omt*omt);
    float lad = __logf(dnum) - 2.0f*__logf(den);
    bool inside = (x >= -1.0f) && (x <= 1.0f);
    yo   = inside ? y   : x;
    lado = inside ? lad : 0.0f;
}
template<int OUTW>
__device__ __forceinline__ void addrow(float v, const float* __restrict__ Wrow, float* acc){
#pragma unroll
    for (int j=0;j<OUTW;++j) acc[j] = fmaf(v, Wrow[j], acc[j]);
}
template<int KIN, int OUT>
__device__ __forceinline__ void dense(const float* x, const float* __restrict__ W,
        const float* __restrict__ B, float* acc){
#pragma unroll
    for (int j=0;j<OUT;++j) acc[j] = B[j];
#pragma unroll
    for (int k=0;k<KIN;++k){
#pragma unroll
        for (int j=0;j<OUT;++j) acc[j] = fmaf(x[k], W[k*OUT+j], acc[j]);
    }
}
__device__ __forceinline__ void mlp_layer0(float t, const float* c,
        const float* __restrict__ W0, const float* __restrict__ B0, float* h)
{
#pragma unroll
    for (int j=0;j<32;++j) h[j] = B0[j];
    addrow<32>(t, W0 + 0*32, h);
    float s, co;
    __sincosf(t*1.0f,       &s,&co); addrow<32>(s, W0+1*32, h); addrow<32>(co, W0+2*32, h);
    __sincosf(t*3.3333333f, &s,&co); addrow<32>(s, W0+3*32, h); addrow<32>(co, W0+4*32, h);
    __sincosf(t*5.6666665f, &s,&co); addrow<32>(s, W0+5*32, h); addrow<32>(co, W0+6*32, h);
    __sincosf(t*8.0f,       &s,&co); addrow<32>(s, W0+7*32, h); addrow<32>(co, W0+8*32, h);
    addrow<32>(c[8], W0 + 9*32, h);
    addrow<32>(c[9], W0 +10*32, h);
    float f = 1.0f;
#pragma unroll
    for (int fi=0; fi<5; ++fi){
        float s8,c8v,s9,c9v;
        __sincosf(c[8]*f, &s8, &c8v);
        __sincosf(c[9]*f, &s9, &c9v);
        addrow<32>(s8,  W0 + (11+4*fi)*32, h);
        addrow<32>(s9,  W0 + (12+4*fi)*32, h);
        addrow<32>(c8v, W0 + (13+4*fi)*32, h);
        addrow<32>(c9v, W0 + (14+4*fi)*32, h);
        f *= 2.0f;
    }
#pragma unroll
    for (int k=0;k<8;++k) addrow<32>(c[k], W0 + (31+k)*32, h);
#pragma unroll
    for (int j=0;j<32;++j) h[j] = lrelu(h[j]);
}
__global__ __launch_bounds__(256,3) void nsf_kernel_f32(
    const float* __restrict__ wi, const float* __restrict__ cond,
    const float* __restrict__ p0_w0, const float* __restrict__ p0_b0,
    const float* __restrict__ p0_w1, const float* __restrict__ p0_b1,
    const float* __restrict__ m1_w0, const float* __restrict__ m1_b0,
    const float* __restrict__ m1_w1, const float* __restrict__ m1_b1,
    const float* __restrict__ m1_w2, const float* __restrict__ m1_b2,
    const float* __restrict__ m0_w0, const float* __restrict__ m0_b0,
    const float* __restrict__ m0_w1, const float* __restrict__ m0_b1,
    const float* __restrict__ m0_w2, const float* __restrict__ m0_b2,
    float* __restrict__ out)
{
    const int i = blockIdx.x*256 + threadIdx.x;
    float2 wv2 = reinterpret_cast<const float2*>(wi)[i];
    float w0v = wv2.x, w1v = wv2.y;
    const float* cp = cond + (size_t)i*10;
    float c[10];
#pragma unroll
    for (int k=0;k<10;++k) c[k] = cp[k];

    float tp[59];
    {
        float h[32], gg[32];
        mlp_layer0(w1v, c, m1_w0, m1_b0, h);
        dense<32,32>(h, m1_w1, m1_b1, gg);
#pragma unroll
        for (int j=0;j<32;++j) gg[j] = lrelu(gg[j]);
        dense<32,59>(gg, m1_w2, m1_b2, tp);
    }
    float y0, ld0; rqs_f32(w0v, tp, y0, ld0);
    {
        float h[32], gg[32];
        mlp_layer0(y0, c, m0_w0, m0_b0, h);
        dense<32,32>(h, m0_w1, m0_b1, gg);
#pragma unroll
        for (int j=0;j<32;++j) gg[j] = lrelu(gg[j]);
        dense<32,59>(gg, m0_w2, m0_b2, tp);
    }
    float y1, ld1; rqs_f32(w1v, tp, y1, ld1);

    float r[4];
    {
        float ph[32];
#pragma unroll
        for (int j=0;j<32;++j) ph[j] = p0_b0[j];
        addrow<32>(c[8], p0_w0 + 0*32, ph);
        addrow<32>(c[9], p0_w0 + 1*32, ph);
        float f = 1.0f;
#pragma unroll
        for (int fi=0; fi<5; ++fi){
            float s8,c8v,s9,c9v;
            __sincosf(c[8]*f, &s8, &c8v);
            __sincosf(c[9]*f, &s9, &c9v);
            addrow<32>(s8,  p0_w0 + (2+4*fi)*32, ph);
            addrow<32>(s9,  p0_w0 + (3+4*fi)*32, ph);
            addrow<32>(c8v, p0_w0 + (4+4*fi)*32, ph);
            addrow<32>(c9v, p0_w0 + (5+4*fi)*32, ph);
            f *= 2.0f;
        }
#pragma unroll
        for (int k=0;k<8;++k) addrow<32>(c[k], p0_w0 + (22+k)*32, ph);
#pragma unroll
        for (int j=0;j<32;++j) ph[j] = lrelu(ph[j]);
        dense<32,4>(ph, p0_w1, p0_b1, r);
    }

    float mu0=r[0], mu1=r[1], ls0=r[2], ls1=r[3];
    float is0 = __expf(-ls0), is1 = __expf(-ls1);
    float e0 = (y0-mu0)*is0, e1 = (y1-mu1)*is1;
    float rr = e0*e0 + e1*e1;
    float lp = -(ls0+ls1) - 1.8378770664093453f - 0.5f*rr + ld0 + ld1;

    reinterpret_cast<float2*>(out)[i] = make_float2(y0, y1);
    out[2*(size_t)N_PTS + i] = lp;
}

extern "C" void kernel_launch(void* const* d_in, const int* in_sizes, int n_in,
                              void* d_out, int out_size, void* d_ws, size_t ws_size,
                              hipStream_t stream)
{
    const float* wi    = (const float*)d_in[0];
    const float* cond  = (const float*)d_in[1];
    const float* p0_w0 = (const float*)d_in[2];
    const float* p0_b0 = (const float*)d_in[3];
    const float* p0_w1 = (const float*)d_in[4];
    const float* p0_b1 = (const float*)d_in[5];
    const float* m1_w0 = (const float*)d_in[6];
    const float* m1_b0 = (const float*)d_in[7];
    const float* m1_w1 = (const float*)d_in[8];
    const float* m1_b1 = (const float*)d_in[9];
    const float* m1_w2 = (const float*)d_in[10];
    const float* m1_b2 = (const float*)d_in[11];
    const float* m0_w0 = (const float*)d_in[12];
    const float* m0_b0 = (const float*)d_in[13];
    const float* m0_w1 = (const float*)d_in[14];
    const float* m0_b1 = (const float*)d_in[15];
    const float* m0_w2 = (const float*)d_in[16];
    const float* m0_b2 = (const float*)d_in[17];
    float* out = (float*)d_out;

    if (ws_size >= (size_t)WS_BYTES) {
        _Float16* wsp = (_Float16*)d_ws;
        hipLaunchKernelGGL(pack_weights, dim3((PACK_ITEMS+255)/256), dim3(256), 0, stream,
            m1_w0, m1_w1, m1_w2, m0_w0, m0_w1, m0_w2, p0_w0, p0_w1,
            m1_b0, m1_b1, m1_b2, m0_b0, m0_b1, m0_b2, p0_b0, wsp);
        hipLaunchKernelGGL(nsf_mfma, dim3(N_PTS/256), dim3(256), 0, stream,
            wi, cond, wsp, p0_b1, out);
    } else {
        hipLaunchKernelGGL(nsf_kernel_f32, dim3(N_PTS/256), dim3(256), 0, stream,
            wi, cond, p0_w0, p0_b0, p0_w1, p0_b1,
            m1_w0, m1_b0, m1_w1, m1_b1, m1_w2, m1_b2,
            m0_w0, m0_b0, m0_w1, m0_b1, m0_w2, m0_b2, out);
    }
}

// Round 16
// 127.455 us; speedup vs baseline: 1.1936x; 1.1557x over previous
//
#include <hip/hip_runtime.h>
#include <math.h>

#define N_PTS 2097152
#define TAILC 0.53974324f   // log(exp(1-0.001)-1)
#define LOG2E 1.4426950408889634f
#define LN2   0.6931471805599453f

typedef unsigned int u32;
typedef _Float16 half8 __attribute__((ext_vector_type(8)));
typedef _Float16 half4 __attribute__((ext_vector_type(4)));
typedef _Float16 h2    __attribute__((ext_vector_type(2)));
typedef __fp16   fp16x2 __attribute__((ext_vector_type(2)));
typedef float float4v  __attribute__((ext_vector_type(4)));

#define MFMA16 __builtin_amdgcn_mfma_f32_16x16x32_f16

__device__ __forceinline__ float lrelu(float x){ return x > 0.0f ? x : 0.01f*x; }
__device__ __forceinline__ float exp2fast(float x){
#if __has_builtin(__builtin_amdgcn_exp2f)
    return __builtin_amdgcn_exp2f(x);
#else
    return exp2f(x);
#endif
}
__device__ __forceinline__ float log2fast(float x){
#if __has_builtin(__builtin_amdgcn_logf)
    return __builtin_amdgcn_logf(x);
#else
    return __log2f(x);
#endif
}
// softplus(x) = ln2 * log2(1 + exp2(x*log2e)); f32-safe for |x| < ~80
__device__ __forceinline__ float softplus_(float x){
    return LN2 * log2fast(1.0f + exp2fast(x * LOG2E));
}
__device__ __forceinline__ half4 pack4(float a0, float a1, float a2, float a3){
#if __has_builtin(__builtin_amdgcn_cvt_pkrtz)
    union { fp16x2 f; h2 h; } lo, hi;
    lo.f = __builtin_amdgcn_cvt_pkrtz(a0, a1);
    hi.f = __builtin_amdgcn_cvt_pkrtz(a2, a3);
    half4 r; r[0]=lo.h[0]; r[1]=lo.h[1]; r[2]=hi.h[0]; r[3]=hi.h[1];
    return r;
#else
    half4 r; r[0]=(_Float16)a0; r[1]=(_Float16)a1; r[2]=(_Float16)a2; r[3]=(_Float16)a3;
    return r;
#endif
}
// packed f16 leaky-relu: v_pk_mul_f16 + v_pk_max_f16 via elementwise builtins
__device__ __forceinline__ h2 lrelu2(h2 x){
#if __has_builtin(__builtin_elementwise_max)
    h2 m = x * (_Float16)0.01f;
    return __builtin_elementwise_max(x, m);
#else
    h2 r; r[0] = (x[0] > (_Float16)0 ? x[0] : x[0]*(_Float16)0.01f);
    r[1] = (x[1] > (_Float16)0 ? x[1] : x[1]*(_Float16)0.01f);
    return r;
#endif
}
// pack 4 f32 -> 4 f16 then leaky-relu in PACKED f16
__device__ __forceinline__ half4 pack4_lrelu(float a0, float a1, float a2, float a3){
#if __has_builtin(__builtin_amdgcn_cvt_pkrtz)
    union { fp16x2 f; h2 h; } lo, hi;
    lo.f = __builtin_amdgcn_cvt_pkrtz(a0, a1);
    hi.f = __builtin_amdgcn_cvt_pkrtz(a2, a3);
    h2 lm = lrelu2(lo.h), hm = lrelu2(hi.h);
    half4 r; r[0]=lm[0]; r[1]=lm[1]; r[2]=hm[0]; r[3]=hm[1];
    return r;
#else
    return pack4(lrelu(a0), lrelu(a1), lrelu(a2), lrelu(a3));
#endif
}
__device__ __forceinline__ half8 join8(half4 a, half4 b){
    half8 r; r[0]=a[0]; r[1]=a[1]; r[2]=a[2]; r[3]=a[3];
    r[4]=b[0]; r[5]=b[1]; r[6]=b[2]; r[7]=b[3];
    return r;
}
__device__ __forceinline__ float fdot2(h2 a, h2 b, float c){
#if __has_builtin(__builtin_amdgcn_fdot2)
    return __builtin_amdgcn_fdot2(a, b, c, false);
#else
    return fmaf((float)a[0],(float)b[0], fmaf((float)a[1],(float)b[1], c));
#endif
}
__device__ __forceinline__ h2 u2h2(u32 u){ union{u32 a; h2 b;} x; x.a=u; return x.b; }

// physical position of logical output o for 32-wide layers (p = 8g + 4n + j, o = 16n+4g+j)
__device__ __host__ constexpr int ppos(int o){
    return 8*((o>>2)&3) + 4*(o>>4) + (o&3);
}
// physical position of logical output m for the 64-wide L2 layer
__device__ __host__ constexpr int qpos(int m){
    return 16*((m>>2)&3) + 8*((m>>4)>>1) + 4*((m>>4)&1) + (m&3);
}
// inverse: logical o at physical p (32-wide)
__device__ __host__ constexpr int pinv(int p){
    return 16*((p>>2)&1) + 4*(p>>3) + (p&3);
}

// Single shared allocation reachable from kernel AND noinline callees.
__device__ __forceinline__ _Float16* waveS(){
    __shared__ _Float16 S[4][4096];    // per-wave [64 rows][64 f16], swizzled
    return &S[0][0];
}
__device__ __forceinline__ half8 rd16(const _Float16* Sw, int row, int u){
    return *(const half8*)(Sw + row*64 + ((u ^ (row&7))<<3));
}
__device__ __forceinline__ void wr16(_Float16* Sw, int row, int u, half8 v){
    *(half8*)(Sw + row*64 + ((u ^ (row&7))<<3)) = v;
}

// ---- packed weights/biases in d_ws ----
#define OFF_M1_W0T 0        // [32][64]
#define OFF_M1_W1T 2048     // [32][32]
#define OFF_M1_W2T 3072     // [64][32]
#define OFF_M0_W0T 5120
#define OFF_M0_W1T 7168
#define OFF_M0_W2T 8192
#define OFF_P0_W0T 10240    // [32][32]
#define WS_F16     11264
// f32 region (byte 22528)
#define FB_M1_B0   0
#define FB_M1_B1   32
#define FB_M1_B2   64       // padded to 64, outputs 0..39 pre-scaled by LOG2E
#define FB_M0_B0   128
#define FB_M0_B1   160
#define FB_M0_B2   192
#define FB_P0_B0   256
#define FB_PW1     288      // 64 u32: p0_w1 packed h2 pairs
#define WS_BYTES   (22528 + 288*4 + 64*4)
#define PACK_ITEMS (WS_F16 + 288 + 64)

__global__ void pack_weights(const float* __restrict__ m1_w0, const float* __restrict__ m1_w1,
                             const float* __restrict__ m1_w2, const float* __restrict__ m0_w0,
                             const float* __restrict__ m0_w1, const float* __restrict__ m0_w2,
                             const float* __restrict__ p0_w0, const float* __restrict__ p0_w1,
                             const float* __restrict__ m1_b0, const float* __restrict__ m1_b1,
                             const float* __restrict__ m1_b2, const float* __restrict__ m0_b0,
                             const float* __restrict__ m0_b1, const float* __restrict__ m0_b2,
                             const float* __restrict__ p0_b0, _Float16* __restrict__ ws)
{
    int idx = blockIdx.x*256 + threadIdx.x;
    if (idx >= PACK_ITEMS) return;
    if (idx < WS_F16) {
        float v = 0.0f;
        if (idx < 2048 || (idx >= 5120 && idx < 7168)) {          // W0T [32][64], k logical
            const float* W = (idx < 2048) ? m1_w0 : m0_w0;
            int r = (idx < 2048) ? idx : idx - 5120;
            int o = r >> 6, k = r & 63;
            if (k < 30)                 v = W[(9+k)*32 + o];
            else if (k >= 32 && k < 41) v = W[(k-32)*32 + o];
        } else if (idx < 3072 || (idx >= 7168 && idx < 8192)) {   // W1T [32][32], k permuted
            const float* W = (idx < 3072) ? m1_w1 : m0_w1;
            int r = (idx < 3072) ? idx - 2048 : idx - 7168;
            int o = r >> 5, p = r & 31;
            v = W[pinv(p)*32 + o];
        } else if (idx < 5120 || (idx >= 8192 && idx < 10240)) {  // W2T [64][32], k permuted, rows<40 scaled
            const float* W = (idx < 5120) ? m1_w2 : m0_w2;
            int r = (idx < 5120) ? idx - 3072 : idx - 8192;
            int o = r >> 5, p = r & 31;
            if (o < 59) {
                v = W[pinv(p)*59 + o];
                if (o < 40) v *= LOG2E;
            }
        } else {                                                  // p0 W0T [32][32], k logical
            int r = idx - 10240;
            int o = r >> 5, k = r & 31;
            if (k < 30) v = p0_w0[k*32 + o];
        }
        ws[idx] = (_Float16)v;
        return;
    }
    float* wsf = (float*)(ws + WS_F16);
    int bi = idx - WS_F16;
    if (bi < 288) {
        float v = 0.0f;
        if      (bi < 32)  v = m1_b0[bi];
        else if (bi < 64)  v = m1_b1[bi-32];
        else if (bi < 128) { int o = bi-64;  if (o < 59) { v = m1_b2[o]; if (o < 40) v *= LOG2E; } }
        else if (bi < 160) v = m0_b0[bi-128];
        else if (bi < 192) v = m0_b1[bi-160];
        else if (bi < 256) { int o = bi-192; if (o < 59) { v = m0_b2[o]; if (o < 40) v *= LOG2E; } }
        else               v = p0_b0[bi-256];
        wsf[bi] = v;
        return;
    }
    int pi = bi - 288;            // 0..63 : p0_w1 packed pairs
    int k2 = pi >> 2, j = pi & 3;
    union{ _Float16 h; unsigned short s; } a, b;
    a.h = (_Float16)p0_w1[(2*k2)*4 + j];
    b.h = (_Float16)p0_w1[(2*k2+1)*4 + j];
    ((u32*)(wsf + FB_PW1))[pi] = (u32)a.s | ((u32)b.s << 16);
}

// ---------- one transform MLP (noinline, emitted once), swapped-operand MFMA ----------
// Inter-layer activations stay IN REGISTERS (lane l's D-output == next-layer B-frag).
// Only L2's output goes to LDS (spline needs cross-lane gather).
__device__ __noinline__ void mlp_lds(int tid,
    const _Float16* __restrict__ W0, const _Float16* __restrict__ W1,
    const _Float16* __restrict__ W2,
    const float* __restrict__ B0p, const float* __restrict__ B1p,
    const float* __restrict__ B2p)
{
    _Float16* Sw = waveS() + (tid>>6)*4096;
    const int l = tid & 63, mrow = l & 15, g = (l >> 4) & 3;

    half8 hB[4];   // packed activations: physical 8g..8g+7 of point 16t+mrow

    // ---- L0: K=64 (2 ksteps), OUT=32; xin from LDS ----
    {
        half8 aW[2][2], bX[4][2];
#pragma unroll
        for (int n=0;n<2;++n)
#pragma unroll
            for (int s=0;s<2;++s)
                aW[n][s] = *(const half8*)(W0 + (16*n+mrow)*64 + 32*s + 8*g);
#pragma unroll
        for (int t=0;t<4;++t){
            int pt = 16*t + mrow;
#pragma unroll
            for (int s=0;s<2;++s) bX[t][s] = rd16(Sw, pt, 4*s+g);
        }
        float4v b0 = *(const float4v*)(B0p + 4*g);
        float4v b1 = *(const float4v*)(B0p + 16 + 4*g);
#pragma unroll
        for (int t=0;t<4;++t){
            float4v a0 = b0, a1 = b1;
            a0 = MFMA16(aW[0][0], bX[t][0], a0, 0,0,0);
            a0 = MFMA16(aW[0][1], bX[t][1], a0, 0,0,0);
            a1 = MFMA16(aW[1][0], bX[t][0], a1, 0,0,0);
            a1 = MFMA16(aW[1][1], bX[t][1], a1, 0,0,0);
            hB[t] = join8(pack4_lrelu(a0[0], a0[1], a0[2], a0[3]),
                          pack4_lrelu(a1[0], a1[1], a1[2], a1[3]));
        }
    }
    // ---- L1: K=32, OUT=32; B from regs, result back to regs (no LDS, no fence) ----
    {
        half8 aW[2];
#pragma unroll
        for (int n=0;n<2;++n) aW[n] = *(const half8*)(W1 + (16*n+mrow)*32 + 8*g);
        float4v b0 = *(const float4v*)(B1p + 4*g);
        float4v b1 = *(const float4v*)(B1p + 16 + 4*g);
#pragma unroll
        for (int t=0;t<4;++t){
            float4v a0 = b0, a1 = b1;
            a0 = MFMA16(aW[0], hB[t], a0, 0,0,0);
            a1 = MFMA16(aW[1], hB[t], a1, 0,0,0);
            hB[t] = join8(pack4_lrelu(a0[0], a0[1], a0[2], a0[3]),
                          pack4_lrelu(a1[0], a1[1], a1[2], a1[3]));
        }
    }
    // ---- L2: K=32, OUT=64 (59 real; outputs 0..39 pre-scaled by LOG2E); to LDS ----
    {
        half8 aW[4];
#pragma unroll
        for (int n=0;n<4;++n) aW[n] = *(const half8*)(W2 + (16*n+mrow)*32 + 8*g);
        float4v bb[4];
#pragma unroll
        for (int n=0;n<4;++n) bb[n] = *(const float4v*)(B2p + 16*n + 4*g);
#pragma unroll
        for (int t=0;t<4;++t){
            float4v a0=bb[0], a1=bb[1], a2=bb[2], a3=bb[3];
            a0 = MFMA16(aW[0], hB[t], a0, 0,0,0);
            a1 = MFMA16(aW[1], hB[t], a1, 0,0,0);
            a2 = MFMA16(aW[2], hB[t], a2, 0,0,0);
            a3 = MFMA16(aW[3], hB[t], a3, 0,0,0);
            int row = 16*t + mrow;
            wr16(Sw, row, 2*g,   join8(pack4(a0[0],a0[1],a0[2],a0[3]),
                                       pack4(a1[0],a1[1],a1[2],a1[3])));
            wr16(Sw, row, 2*g+1, join8(pack4(a2[0],a2[1],a2[2],a2[3]),
                                       pack4(a3[0],a3[1],a3[2],a3[3])));
        }
    }
    __threadfence_block();
}

// ---------- spline (noinline, emitted once) ----------
// uw/uh arrive pre-scaled by LOG2E -> exp2 direct, NO max subtraction.
// Single merged walk: both (cum,wv) and (hcum,hv) selected under u01>=cum.
__device__ __noinline__ float2 rqs_lds(float x, int tid)
{
    const int l = tid & 63;
    const int swz = l & 7;
    const _Float16* Sw = waveS() + (tid>>6)*4096;

    // widths+heights live in units {0,1,2,3,4,6}; derivs read dynamically below.
    half8 R[8];
    R[0]=rd16(Sw,l,0); R[1]=rd16(Sw,l,1); R[2]=rd16(Sw,l,2);
    R[3]=rd16(Sw,l,3); R[4]=rd16(Sw,l,4); R[6]=rd16(Sw,l,6);
    R[5]=R[4]; R[7]=R[6];   // dead (q never hits 5/7 for m<40); avoids UB

    float xc = fminf(fmaxf(x,-1.0f),1.0f);
    float u01 = fmaf(xc, 0.5f, 0.5f);       // walk in normalized cum-space

    float w[20], h[20];
#pragma unroll
    for (int i=0;i<20;++i){ int q = qpos(i);    w[i] = exp2fast((float)R[q>>3][q&7]); }
#pragma unroll
    for (int i=0;i<20;++i){ int q = qpos(20+i); h[i] = exp2fast((float)R[q>>3][q&7]); }
    float sw = 0.f, sh = 0.f;
#pragma unroll
    for (int i=0;i<20;++i){ sw += w[i]; sh += h[i]; }
    float invw = 0.98f / sw;
    float invh = 0.98f / sh;

    int idx = 0;
    float cumL = 0.0f, wvL = 1.0f, hcumL = 0.0f, hvL = 1.0f;
    float cum = 0.f, hcum = 0.f;
#pragma unroll
    for (int i=0;i<20;++i){
        float wv = fmaf(invw, w[i], 0.001f);
        float hv = fmaf(invh, h[i], 0.001f);
        if (u01 >= cum){ idx = i; cumL = cum; wvL = wv; hcumL = hcum; hvL = hv; }
        cum += wv; hcum += hv;
    }

    // derivs: udl = idx>0 ? tp[39+idx] : TAILC ; udr = idx<19 ? tp[40+idx] : TAILC
    auto rdq = [&](int m)->float{
        int q = 16*((m>>2)&3) + 8*((m>>4)>>1) + 4*((m>>4)&1) + (m&3);
        return (float)Sw[l*64 + (((q>>3) ^ swz)<<3) + (q&7)];
    };
    float dl = rdq(39+idx);
    float dr = rdq(40+idx);
    float udl = (idx>0)  ? dl : TAILC;
    float udr = (idx<19) ? dr : TAILC;

    float inD   = 0.001f + softplus_(udl);
    float inDp1 = 0.001f + softplus_(udr);
    float inDelta = hvL / wvL;              // (2hvL)/(2wvL)
    float inH  = 2.0f * hvL;
    float inCh = fmaf(2.0f, hcumL, -1.0f);
    float th  = (u01 - cumL) / wvL;         // == (xc - inCw)/inW
    float omt = 1.0f - th;
    float t1  = th * omt;
    float num = inH * (inDelta*th*th + inD*t1);
    float den = inDelta + (inD + inDp1 - 2.0f*inDelta)*t1;
    float y = inCh + num/den;
    float dnum = inDelta*inDelta*(inDp1*th*th + 2.0f*inDelta*t1 + inD*omt*omt);
    float lad = LN2 * (log2fast(dnum) - 2.0f*log2fast(den));
    bool inside = (x >= -1.0f) && (x <= 1.0f);
    return make_float2(inside ? y : x, inside ? lad : 0.0f);
}

__global__ __launch_bounds__(256,4) void nsf_mfma(
    const float* __restrict__ wi, const float* __restrict__ cond,
    const _Float16* __restrict__ wsp,
    const float* __restrict__ p0_b1,
    float* __restrict__ out)
{
    const int tid = threadIdx.x;
    const int l = tid & 63, wid = tid >> 6;
    const int i = blockIdx.x*256 + wid*64 + l;
    _Float16* Sw = waveS() + wid*4096;
    const int mrow = l & 15, g = (l >> 4) & 3;
    const float* wsf = (const float*)(wsp + WS_F16);

    float2 wv2 = reinterpret_cast<const float2*>(wi)[i];
    float w0v = wv2.x, w1v = wv2.y;
    float c[10];
    {
        const float2* cp2 = reinterpret_cast<const float2*>(cond + (size_t)i*10);
#pragma unroll
        for (int k=0;k<5;++k){ float2 t2 = cp2[k]; c[2*k]=t2.x; c[2*k+1]=t2.y; }
    }

    // cond_e -> f16 chunks A0..A3 (cols 0..31, incl. 2 zero pads)
    half8 A0, A1, A2, A3, Z;
#pragma unroll
    for (int j=0;j<8;++j) Z[j] = (_Float16)0.0f;
    {
        _Float16 ce[30];
        ce[0] = (_Float16)c[8];
        ce[1] = (_Float16)c[9];
        float f = 1.0f;
#pragma unroll
        for (int fi=0; fi<5; ++fi){
            float s8,c8v,s9,c9v;
            __sincosf(c[8]*f, &s8, &c8v);
            __sincosf(c[9]*f, &s9, &c9v);
            ce[2+4*fi+0]=(_Float16)s8;  ce[2+4*fi+1]=(_Float16)s9;
            ce[2+4*fi+2]=(_Float16)c8v; ce[2+4*fi+3]=(_Float16)c9v;
            f *= 2.0f;
        }
#pragma unroll
        for (int k=0;k<8;++k) ce[22+k] = (_Float16)c[k];
#pragma unroll
        for (int j=0;j<8;++j){ A0[j]=ce[j]; A1[j]=ce[8+j]; A2[j]=ce[16+j]; }
#pragma unroll
        for (int j=0;j<8;++j) A3[j] = (j<6) ? ce[24+j] : (_Float16)0.0f;
    }

    auto mkPE = [&](float t, half8& P0, half8& P1){
        float s1,c1v,s2,c2v,s3,c3v,s4,c4v;
        __sincosf(t*1.0f,       &s1,&c1v);
        __sincosf(t*3.3333333f, &s2,&c2v);
        __sincosf(t*5.6666665f, &s3,&c3v);
        __sincosf(t*8.0f,       &s4,&c4v);
        P0[0]=(_Float16)t;   P0[1]=(_Float16)s1; P0[2]=(_Float16)c1v; P0[3]=(_Float16)s2;
        P0[4]=(_Float16)c2v; P0[5]=(_Float16)s3; P0[6]=(_Float16)c3v; P0[7]=(_Float16)s4;
        P1 = Z; P1[0] = (_Float16)c4v;
    };

    // ---- m1: stage xin(w1v), MLP, spline on w0 ----
    half8 P0, P1;
    mkPE(w1v, P0, P1);
    wr16(Sw,l,0,A0); wr16(Sw,l,1,A1); wr16(Sw,l,2,A2); wr16(Sw,l,3,A3);
    wr16(Sw,l,4,P0); wr16(Sw,l,5,P1); wr16(Sw,l,6,Z);  wr16(Sw,l,7,Z);
    __threadfence_block();
    mlp_lds(tid, wsp+OFF_M1_W0T, wsp+OFF_M1_W1T, wsp+OFF_M1_W2T,
            wsf+FB_M1_B0, wsf+FB_M1_B1, wsf+FB_M1_B2);
    float2 r0 = rqs_lds(w0v, tid);
    float y0 = r0.x, ld0 = r0.y;

    // ---- m0: stage xin(y0), MLP, spline on w1 ----
    mkPE(y0, P0, P1);
    wr16(Sw,l,0,A0); wr16(Sw,l,1,A1); wr16(Sw,l,2,A2); wr16(Sw,l,3,A3);
    wr16(Sw,l,4,P0); wr16(Sw,l,5,P1); wr16(Sw,l,6,Z);  wr16(Sw,l,7,Z);
    __threadfence_block();
    mlp_lds(tid, wsp+OFF_M0_W0T, wsp+OFF_M0_W1T, wsp+OFF_M0_W2T,
            wsf+FB_M0_B0, wsf+FB_M0_B1, wsf+FB_M0_B2);
    float2 r1 = rqs_lds(w1v, tid);
    float y1 = r1.x, ld1 = r1.y;

    // ---- p0: cond_e(30,+2pad) -> 32 (lrelu) via swapped MFMA ----
    wr16(Sw,l,0,A0); wr16(Sw,l,1,A1); wr16(Sw,l,2,A2); wr16(Sw,l,3,A3);
    __threadfence_block();
    {
        half8 aW[2], bC[4];
#pragma unroll
        for (int n=0;n<2;++n) aW[n] = *(const half8*)(wsp + OFF_P0_W0T + (16*n+mrow)*32 + 8*g);
#pragma unroll
        for (int t=0;t<4;++t) bC[t] = rd16(Sw, 16*t+mrow, g);
        const float* PB = wsf + FB_P0_B0;
        float4v b0 = *(const float4v*)(PB + 4*g);
        float4v b1 = *(const float4v*)(PB + 16 + 4*g);
#pragma unroll
        for (int t=0;t<4;++t){
            float4v a0 = b0, a1 = b1;
            a0 = MFMA16(aW[0], bC[t], a0, 0,0,0);
            a1 = MFMA16(aW[1], bC[t], a1, 0,0,0);
            wr16(Sw, 16*t+mrow, g, join8(
                pack4_lrelu(a0[0], a0[1], a0[2], a0[3]),
                pack4_lrelu(a1[0], a1[1], a1[2], a1[3])));
        }
    }
    __threadfence_block();

    // ---- tail: per-thread 32 -> 4 via fdot2 (permuted unpack) ----
    float r4[4] = {p0_b1[0], p0_b1[1], p0_b1[2], p0_b1[3]};
    {
        half8 Tq[4];
#pragma unroll
        for (int u=0;u<4;++u) Tq[u] = rd16(Sw, l, u);
        const u32* pw = (const u32*)(wsf + FB_PW1);
#pragma unroll
        for (int k2=0;k2<16;++k2){
            int p = ppos(2*k2);                 // pair (2k2, 2k2+1) is position-adjacent
            h2 x; x[0] = Tq[p>>3][p&7]; x[1] = Tq[(p+1)>>3][(p+1)&7];
#pragma unroll
            for (int j=0;j<4;++j) r4[j] = fdot2(x, u2h2(pw[k2*4+j]), r4[j]);
        }
    }

    float mu0=r4[0], mu1=r4[1], ls0=r4[2], ls1=r4[3];
    float is0 = __expf(-ls0), is1 = __expf(-ls1);
    float e0 = (y0-mu0)*is0, e1 = (y1-mu1)*is1;
    float rr = e0*e0 + e1*e1;
    float lp = -(ls0+ls1) - 1.8378770664093453f - 0.5f*rr + ld0 + ld1;

    reinterpret_cast<float2*>(out)[i] = make_float2(y0, y1);
    out[2*(size_t)N_PTS + i] = lp;
}

// ---------------- fallback all-f32 kernel (known-good R1) ----------------
__device__ __forceinline__ float softplus_ref(float x){
    return fmaxf(x, 0.0f) + log1pf(__expf(-fabsf(x)));
}
__device__ __forceinline__ void rqs_f32(float x, float* tp, float& yo, float& lado)
{
    float mw = tp[0];
#pragma unroll
    for (int i=1;i<20;++i) mw = fmaxf(mw, tp[i]);
    float sw = 0.f;
#pragma unroll
    for (int i=0;i<20;++i){ tp[i] = __expf(tp[i]-mw); sw += tp[i]; }
    float invw = 0.98f / sw;
    float mh = tp[20];
#pragma unroll
    for (int i=1;i<20;++i) mh = fmaxf(mh, tp[20+i]);
    float sh = 0.f;
#pragma unroll
    for (int i=0;i<20;++i){ tp[20+i] = __expf(tp[20+i]-mh); sh += tp[20+i]; }
    float invh = 0.98f / sh;
    float xc = fminf(fmaxf(x,-1.0f),1.0f);
    float cum = 0.f; int idx = 0;
    float inCw = -1.0f, inW = 1.0f;
#pragma unroll
    for (int i=0;i<20;++i){
        float wv = fmaf(invw, tp[i], 0.001f);
        float cwL = (i==0) ? -1.0f : fmaf(2.0f, cum, -1.0f);
        float cumN = cum + wv;
        float cwR = (i==19) ? 1.0f : fmaf(2.0f, cumN, -1.0f);
        if (xc >= cwL){ idx = i; inCw = cwL; inW = cwR - cwL; }
        cum = cumN;
    }
    float hcum = 0.f; float inCh = -1.0f, inH = 1.0f;
#pragma unroll
    for (int i=0;i<20;++i){
        float hv = fmaf(invh, tp[20+i], 0.001f);
        float chL = (i==0) ? -1.0f : fmaf(2.0f, hcum, -1.0f);
        float hcumN = hcum + hv;
        float chR = (i==19) ? 1.0f : fmaf(2.0f, hcumN, -1.0f);
        if (i == idx){ inCh = chL; inH = chR - chL; }
        hcum = hcumN;
    }
    float udl = TAILC, udr = TAILC;
#pragma unroll
    for (int t=0;t<19;++t){
        if (idx == t+1) udl = tp[40+t];
        if (idx == t)   udr = tp[40+t];
    }
    float inD   = 0.001f + softplus_ref(udl);
    float inDp1 = 0.001f + softplus_ref(udr);
    float inDelta = inH / inW;
    float th  = (xc - inCw) / inW;
    float omt = 1.0f - th;
    float t1  = th * omt;
    float num = inH * (inDelta*th*th + inD*t1);
    float den = inDelta + (inD + inDp1 - 2.0f*inDelta)*t1;
    float y = inCh + num/den;
    float dnum = inDelta*inDelta*(inDp1*th*th + 2.0f*inDelta*t1 + inD*omt*omt);
    float lad = __logf(dnum) - 2.0f*__logf(den);
    bool inside = (x >= -1.0f) && (x <= 1.0f);
    yo   = inside ? y   : x;
    lado = inside ? lad : 0.0f;
}
template<int OUTW>
__device__ __forceinline__ void addrow(float v, const float* __restrict__ Wrow, float* acc){
#pragma unroll
    for (int j=0;j<OUTW;++j) acc[j] = fmaf(v, Wrow[j], acc[j]);
}
template<int KIN, int OUT>
__device__ __forceinline__ void dense(const float* x, const float* __restrict__ W,
        const float* __restrict__ B, float* acc){
#pragma unroll
    for (int j=0;j<OUT;++j) acc[j] = B[j];
#pragma unroll
    for (int k=0;k<KIN;++k){
#pragma unroll
        for (int j=0;j<OUT;++j) acc[j] = fmaf(x[k], W[k*OUT+j], acc[j]);
    }
}
__device__ __forceinline__ void mlp_layer0(float t, const float* c,
        const float* __restrict__ W0, const float* __restrict__ B0, float* h)
{
#pragma unroll
    for (int j=0;j<32;++j) h[j] = B0[j];
    addrow<32>(t, W0 + 0*32, h);
    float s, co;
    __sincosf(t*1.0f,       &s,&co); addrow<32>(s, W0+1*32, h); addrow<32>(co, W0+2*32, h);
    __sincosf(t*3.3333333f, &s,&co); addrow<32>(s, W0+3*32, h); addrow<32>(co, W0+4*32, h);
    __sincosf(t*5.6666665f, &s,&co); addrow<32>(s, W0+5*32, h); addrow<32>(co, W0+6*32, h);
    __sincosf(t*8.0f,       &s,&co); addrow<32>(s, W0+7*32, h); addrow<32>(co, W0+8*32, h);
    addrow<32>(c[8], W0 + 9*32, h);
    addrow<32>(c[9], W0 +10*32, h);
    float f = 1.0f;
#pragma unroll
    for (int fi=0; fi<5; ++fi){
        float s8,c8v,s9,c9v;
        __sincosf(c[8]*f, &s8, &c8v);
        __sincosf(c[9]*f, &s9, &c9v);
        addrow<32>(s8,  W0 + (11+4*fi)*32, h);
        addrow<32>(s9,  W0 + (12+4*fi)*32, h);
        addrow<32>(c8v, W0 + (13+4*fi)*32, h);
        addrow<32>(c9v, W0 + (14+4*fi)*32, h);
        f *= 2.0f;
    }
#pragma unroll
    for (int k=0;k<8;++k) addrow<32>(c[k], W0 + (31+k)*32, h);
#pragma unroll
    for (int j=0;j<32;++j) h[j] = lrelu(h[j]);
}
__global__ __launch_bounds__(256,3) void nsf_kernel_f32(
    const float* __restrict__ wi, const float* __restrict__ cond,
    const float* __restrict__ p0_w0, const float* __restrict__ p0_b0,
    const float* __restrict__ p0_w1, const float* __restrict__ p0_b1,
    const float* __restrict__ m1_w0, const float* __restrict__ m1_b0,
    const float* __restrict__ m1_w1, const float* __restrict__ m1_b1,
    const float* __restrict__ m1_w2, const float* __restrict__ m1_b2,
    const float* __restrict__ m0_w0, const float* __restrict__ m0_b0,
    const float* __restrict__ m0_w1, const float* __restrict__ m0_b1,
    const float* __restrict__ m0_w2, const float* __restrict__ m0_b2,
    float* __restrict__ out)
{
    const int i = blockIdx.x*256 + threadIdx.x;
    float2 wv2 = reinterpret_cast<const float2*>(wi)[i];
    float w0v = wv2.x, w1v = wv2.y;
    const float* cp = cond + (size_t)i*10;
    float c[10];
#pragma unroll
    for (int k=0;k<10;++k) c[k] = cp[k];

    float tp[59];
    {
        float h[32], gg[32];
        mlp_layer0(w1v, c, m1_w0, m1_b0, h);
        dense<32,32>(h, m1_w1, m1_b1, gg);
#pragma unroll
        for (int j=0;j<32;++j) gg[j] = lrelu(gg[j]);
        dense<32,59>(gg, m1_w2, m1_b2, tp);
    }
    float y0, ld0; rqs_f32(w0v, tp, y0, ld0);
    {
        float h[32], gg[32];
        mlp_layer0(y0, c, m0_w0, m0_b0, h);
        dense<32,32>(h, m0_w1, m0_b1, gg);
#pragma unroll
        for (int j=0;j<32;++j) gg[j] = lrelu(gg[j]);
        dense<32,59>(gg, m0_w2, m0_b2, tp);
    }
    float y1, ld1; rqs_f32(w1v, tp, y1, ld1);

    float r[4];
    {
        float ph[32];
#pragma unroll
        for (int j=0;j<32;++j) ph[j] = p0_b0[j];
        addrow<32>(c[8], p0_w0 + 0*32, ph);
        addrow<32>(c[9], p0_w0 + 1*32, ph);
        float f = 1.0f;
#pragma unroll
        for (int fi=0; fi<5; ++fi){
            float s8,c8v,s9,c9v;
            __sincosf(c[8]*f, &s8, &c8v);
            __sincosf(c[9]*f, &s9, &c9v);
            addrow<32>(s8,  p0_w0 + (2+4*fi)*32, ph);
            addrow<32>(s9,  p0_w0 + (3+4*fi)*32, ph);
            addrow<32>(c8v, p0_w0 + (4+4*fi)*32, ph);
            addrow<32>(c9v, p0_w0 + (5+4*fi)*32, ph);
            f *= 2.0f;
        }
#pragma unroll
        for (int k=0;k<8;++k) addrow<32>(c[k], p0_w0 + (22+k)*32, ph);
#pragma unroll
        for (int j=0;j<32;++j) ph[j] = lrelu(ph[j]);
        dense<32,4>(ph, p0_w1, p0_b1, r);
    }

    float mu0=r[0], mu1=r[1], ls0=r[2], ls1=r[3];
    float is0 = __expf(-ls0), is1 = __expf(-ls1);
    float e0 = (y0-mu0)*is0, e1 = (y1-mu1)*is1;
    float rr = e0*e0 + e1*e1;
    float lp = -(ls0+ls1) - 1.8378770664093453f - 0.5f*rr + ld0 + ld1;

    reinterpret_cast<float2*>(out)[i] = make_float2(y0, y1);
    out[2*(size_t)N_PTS + i] = lp;
}

extern "C" void kernel_launch(void* const* d_in, const int* in_sizes, int n_in,
                              void* d_out, int out_size, void* d_ws, size_t ws_size,
                              hipStream_t stream)
{
    const float* wi    = (const float*)d_in[0];
    const float* cond  = (const float*)d_in[1];
    const float* p0_w0 = (const float*)d_in[2];
    const float* p0_b0 = (const float*)d_in[3];
    const float* p0_w1 = (const float*)d_in[4];
    const float* p0_b1 = (const float*)d_in[5];
    const float* m1_w0 = (const float*)d_in[6];
    const float* m1_b0 = (const float*)d_in[7];
    const float* m1_w1 = (const float*)d_in[8];
    const float* m1_b1 = (const float*)d_in[9];
    const float* m1_w2 = (const float*)d_in[10];
    const float* m1_b2 = (const float*)d_in[11];
    const float* m0_w0 = (const float*)d_in[12];
    const float* m0_b0 = (const float*)d_in[13];
    const float* m0_w1 = (const float*)d_in[14];
    const float* m0_b1 = (const float*)d_in[15];
    const float* m0_w2 = (const float*)d_in[16];
    const float* m0_b2 = (const float*)d_in[17];
    float* out = (float*)d_out;

    if (ws_size >= (size_t)WS_BYTES) {
        _Float16* wsp = (_Float16*)d_ws;
        hipLaunchKernelGGL(pack_weights, dim3((PACK_ITEMS+255)/256), dim3(256), 0, stream,
            m1_w0, m1_w1, m1_w2, m0_w0, m0_w1, m0_w2, p0_w0, p0_w1,
            m1_b0, m1_b1, m1_b2, m0_b0, m0_b1, m0_b2, p0_b0, wsp);
        hipLaunchKernelGGL(nsf_mfma, dim3(N_PTS/256), dim3(256), 0, stream,
            wi, cond, wsp, p0_b1, out);
    } else {
        hipLaunchKernelGGL(nsf_kernel_f32, dim3(N_PTS/256), dim3(256), 0, stream,
            wi, cond, p0_w0, p0_b0, p0_w1, p0_b1,
            m1_w0, m1_b0, m1_w1, m1_b1, m1_w2, m1_b2,
            m0_w0, m0_b0, m0_w1, m0_b1, m0_w2, m0_b2, out);
    }
}